// Round 4
// baseline (171.716 us; speedup 1.0000x reference)
//
#include <hip/hip_runtime.h>
#include <math.h>
#include <stdint.h>

#define NB 8
#define P_TOTAL 13343
#define NCLS 80
#define KTOP 1000
#define PPAD 16384
#define D_SCORE_THR 0.05
#define D_IOU_THR 0.6

// ---------------- helpers ----------------

__device__ __forceinline__ double sig64(double x) {
    if (x >= 0.0) {
        double e = exp(-x);
        return 1.0 / (1.0 + e);
    } else {
        double e = exp(x);
        return e / (1.0 + e);
    }
}

// key = score bits (top 50) | (0x3FFF - idx): descending sort => score desc, idx asc
__device__ __forceinline__ uint64_t pack_key(double s, int p) {
    uint64_t b = (uint64_t)__double_as_longlong(s);
    return (b & ~0x3FFFull) | (uint64_t)(0x3FFF - p);
}

__device__ __forceinline__ uint64_t rl64(uint64_t v, int l) {
    uint32_t lo = (uint32_t)__builtin_amdgcn_readlane((int)(uint32_t)v, l);
    uint32_t hi = (uint32_t)__builtin_amdgcn_readlane((int)(uint32_t)(v >> 32), l);
    return ((uint64_t)hi << 32) | lo;
}

// Bitonic sort (descending) on uint64 keys in LDS. n power of two.
__device__ void bitonic_u64(uint64_t* sk, int n, int tid, int nthr) {
    for (int k2 = 2; k2 <= n; k2 <<= 1) {
        for (int j = k2 >> 1; j > 0; j >>= 1) {
            for (int t = tid; t < (n >> 1); t += nthr) {
                int i = ((t & ~(j - 1)) << 1) | (t & (j - 1));
                int l = i | j;
                uint64_t a = sk[i], b = sk[l];
                bool prec = (a > b);
                bool desc = ((i & k2) == 0);
                if (prec != desc) { sk[i] = b; sk[l] = a; }
            }
            __syncthreads();
        }
    }
}

// ---------------- S0: scores/classes -> packed keys ----------------

__global__ __launch_bounds__(256) void k_scores(
    const float* __restrict__ c0, const float* __restrict__ c1, const float* __restrict__ c2,
    const float* __restrict__ c3, const float* __restrict__ c4,
    const float* __restrict__ n0, const float* __restrict__ n1, const float* __restrict__ n2,
    const float* __restrict__ n3, const float* __restrict__ n4,
    uint64_t* __restrict__ packed, int* __restrict__ classes)
{
    int gid = blockIdx.x * 256 + threadIdx.x;
    if (gid >= NB * PPAD) return;
    int b = gid >> 14;
    int p = gid & (PPAD - 1);
    if (p >= P_TOTAL) { packed[gid] = 0; return; }

    int base, hw;
    const float* cls;
    const float* cnt;
    if (p < 10000)      { base = 0;     hw = 10000; cls = c0; cnt = n0; }
    else if (p < 12500) { base = 10000; hw = 2500;  cls = c1; cnt = n1; }
    else if (p < 13125) { base = 12500; hw = 625;   cls = c2; cnt = n2; }
    else if (p < 13294) { base = 13125; hw = 169;   cls = c3; cnt = n3; }
    else                { base = 13294; hw = 49;    cls = c4; cnt = n4; }
    int yx = p - base;

    const float* cp = cls + (size_t)b * NCLS * hw + yx;
    float m = -3.4e38f;
    int am = 0;
    for (int c = 0; c < NCLS; ++c) {
        float v = cp[(size_t)c * hw];
        if (v > m) { m = v; am = c; }   // first max, matches jnp.argmax
    }
    float cv = cnt[(size_t)b * hw + yx];
    double s = sqrt(sig64((double)m) * sig64((double)cv));

    packed[gid] = pack_key(s, p);
    classes[(size_t)b * P_TOTAL + p] = am + 1;
}

// ---------------- S1: key-bit histogram select + sort -> top 1024 ----------------

__global__ __launch_bounds__(512) void k_select(
    const uint64_t* __restrict__ packed, uint64_t* __restrict__ tkeys)
{
    __shared__ uint32_t hist[2048];
    __shared__ uint64_t cand[2048];
    __shared__ uint32_t chs[64];
    __shared__ int sB1, sC1, sB2, sCnt;
    int b = blockIdx.x;
    int tid = threadIdx.x;
    const uint64_t* pk = packed + (size_t)b * PPAD;

    for (int t = tid; t < 2048; t += 512) hist[t] = 0;
    __syncthreads();

    // pass 1: bins = top 11 key bits (monotone in key)
    for (int t = tid; t < PPAD; t += 512) {
        uint32_t bin = (uint32_t)(pk[t] >> 53);
        atomicAdd(&hist[bin], 1u);
    }
    __syncthreads();
    if (tid < 64) {
        uint32_t ssum = 0;
        for (int i = 0; i < 32; ++i) ssum += hist[tid * 32 + i];
        chs[tid] = ssum;
    }
    __syncthreads();
    if (tid == 0) {
        int acc = 0, c = 63;
        for (; c > 0; --c) { if (acc + (int)chs[c] >= 1024) break; acc += (int)chs[c]; }
        int bfound = c * 32;
        for (int bb = c * 32 + 31; bb >= c * 32; --bb) {
            if (acc + (int)hist[bb] >= 1024) { bfound = bb; break; }
            acc += (int)hist[bb];
        }
        sB1 = bfound; sC1 = acc;   // acc = count of keys with bin > sB1
    }
    __syncthreads();
    uint32_t B1 = (uint32_t)sB1;
    for (int t = tid; t < 2048; t += 512) hist[t] = 0;
    __syncthreads();

    // pass 2: refine within crossing bin using next 11 key bits
    for (int t = tid; t < PPAD; t += 512) {
        uint64_t key = pk[t];
        if ((uint32_t)(key >> 53) == B1)
            atomicAdd(&hist[(uint32_t)(key >> 42) & 2047u], 1u);
    }
    __syncthreads();
    if (tid < 64) {
        uint32_t ssum = 0;
        for (int i = 0; i < 32; ++i) ssum += hist[tid * 32 + i];
        chs[tid] = ssum;
    }
    __syncthreads();
    if (tid == 0) {
        int acc = sC1, c = 63;
        for (; c > 0; --c) { if (acc + (int)chs[c] >= 1024) break; acc += (int)chs[c]; }
        int bfound = c * 32;
        for (int bb = c * 32 + 31; bb >= c * 32; --bb) {
            if (acc + (int)hist[bb] >= 1024) { bfound = bb; break; }
            acc += (int)hist[bb];
        }
        sB2 = bfound;
        sCnt = 0;
    }
    __syncthreads();
    uint32_t B2 = (uint32_t)sB2;

    // pass 3: compact candidates (exact-rank superset; sort canonicalizes)
    for (int t = tid; t < PPAD; t += 512) {
        uint64_t key = pk[t];
        uint32_t k1 = (uint32_t)(key >> 53);
        bool pred = (k1 > B1) ||
                    (k1 == B1 && ((uint32_t)(key >> 42) & 2047u) >= B2);
        if (pred) {
            int slot = atomicAdd(&sCnt, 1);
            if (slot < 2048) cand[slot] = key;
        }
    }
    __syncthreads();
    int cnt = sCnt < 2048 ? sCnt : 2048;

    if (cnt <= 1024) {
        for (int t = tid; t < 1024; t += 512) if (t >= cnt) cand[t] = 0;
        __syncthreads();
        bitonic_u64(cand, 1024, tid, 512);
    } else {
        for (int t = tid; t < 2048; t += 512) if (t >= cnt) cand[t] = 0;
        __syncthreads();
        bitonic_u64(cand, 2048, tid, 512);
    }

    for (int t = tid; t < 1024; t += 512)
        tkeys[(size_t)b * 1024 + t] = cand[t];
}

// ---------------- S2: fused box gather + offsets + mask matrix ----------------

__global__ __launch_bounds__(256) void k_boxmask(
    const uint64_t* __restrict__ tkeys, const int* __restrict__ classes,
    const float* __restrict__ r0, const float* __restrict__ r1, const float* __restrict__ r2,
    const float* __restrict__ r3, const float* __restrict__ r4,
    float* __restrict__ outs, float* __restrict__ outc, float* __restrict__ outb,
    uint64_t* __restrict__ keepw,
    uint64_t* __restrict__ M, uint64_t* __restrict__ D)
{
    __shared__ double lx1[1024], ly1[1024], lx2[1024], ly2[1024], lar[1024];
    __shared__ double red[256];
    int bid = blockIdx.x;
    int b = bid >> 4, rb = bid & 15;
    int tid = threadIdx.x;

    double vx1[4], vy1[4], vx2[4], vy2[4], sc[4];
    int cls_[4];
    double lmax = -1e300;

#pragma unroll
    for (int k = 0; k < 4; ++k) {
        int j = tid + k * 256;
        uint64_t key = tkeys[(size_t)b * 1024 + j];
        int idx = 0x3FFF - (int)(key & 0x3FFF);
        idx = idx < 0 ? 0 : (idx > P_TOTAL - 1 ? P_TOTAL - 1 : idx);
        double s = __longlong_as_double((long long)(key & ~0x3FFFull));

        int base, w, hw, st;
        const float* reg;
        if (idx < 10000)      { base = 0;     w = 100; hw = 10000; st = 8;   reg = r0; }
        else if (idx < 12500) { base = 10000; w = 50;  hw = 2500;  st = 16;  reg = r1; }
        else if (idx < 13125) { base = 12500; w = 25;  hw = 625;   st = 32;  reg = r2; }
        else if (idx < 13294) { base = 13125; w = 13;  hw = 169;   st = 64;  reg = r3; }
        else                  { base = 13294; w = 7;   hw = 49;    st = 128; reg = r4; }
        int yx = idx - base;
        int y = yx / w;
        int x = yx - y * w;
        double sx = (double)(x * st + st / 2);
        double sy = (double)(y * st + st / 2);
        const float* rp = reg + (size_t)b * 4 * hw + yx;
        double x1 = sx - (double)rp[0];
        double y1 = sy - (double)rp[hw];
        double x2 = sx + (double)rp[2 * (size_t)hw];
        double y2 = sy + (double)rp[3 * (size_t)hw];
        int cv = classes[(size_t)b * P_TOTAL + idx];

        bool valid = (j < KTOP) && (s >= D_SCORE_THR);
        if (j < KTOP) {
            lmax = fmax(lmax, valid ? x1 : 0.0);
            lmax = fmax(lmax, valid ? y1 : 0.0);
            lmax = fmax(lmax, valid ? x2 : 0.0);
            lmax = fmax(lmax, valid ? y2 : 0.0);
        }
        vx1[k] = x1; vy1[k] = y1; vx2[k] = x2; vy2[k] = y2;
        sc[k] = s; cls_[k] = cv;

        uint64_t bal = __ballot(valid);
        if (rb == 0 && (tid & 63) == 0) keepw[(size_t)b * 16 + (tid >> 6) + 4 * k] = bal;
    }

    red[tid] = lmax;
    __syncthreads();
    for (int s2 = 128; s2 > 0; s2 >>= 1) {
        if (tid < s2) red[tid] = fmax(red[tid], red[tid + s2]);
        __syncthreads();
    }
    double offscale = red[0] + 1.0;
    __syncthreads();

#pragma unroll
    for (int k = 0; k < 4; ++k) {
        int j = tid + k * 256;
        double o = (double)cls_[k] * offscale;
        double ox1 = vx1[k] + o, oy1 = vy1[k] + o;
        double ox2 = vx2[k] + o, oy2 = vy2[k] + o;
        lx1[j] = ox1; ly1[j] = oy1; lx2[j] = ox2; ly2[j] = oy2;
        lar[j] = (ox2 - ox1 + 1.0) * (oy2 - oy1 + 1.0);
        if (rb == 0 && j < KTOP) {
            size_t ix = (size_t)b * 1024 + j;
            outs[ix] = (float)sc[k];
            outc[ix] = (float)cls_[k];
            ((float4*)outb)[ix] = make_float4((float)vx1[k], (float)vy1[k],
                                              (float)vx2[k], (float)vy2[k]);
        }
    }
    __syncthreads();

    int rl = tid >> 2;          // 0..63
    int wq = tid & 3;
    int r = rb * 64 + rl;
    double rx1 = lx1[r], ry1 = ly1[r], rx2 = lx2[r], ry2 = ly2[r], ra = lar[r];

#pragma unroll
    for (int ww = 0; ww < 4; ++ww) {
        int w = ww * 4 + wq;
        uint64_t bits = 0;
        if (w * 64 + 63 > r) {
            for (int kk = 0; kk < 64; ++kk) {
                int j = w * 64 + kk;
                double xmn = fmax(lx1[j], rx1);
                double ymn = fmax(ly1[j], ry1);
                double xmx = fmin(lx2[j], rx2);
                double ymx = fmin(ly2[j], ry2);
                double iw = xmx - xmn; iw = iw < 0.0 ? 0.0 : iw;
                double ih = ymx - ymn; ih = ih < 0.0 ? 0.0 : ih;
                double inter = iw * ih;
                double iou = inter / (ra + lar[j] - inter);   // f64 div: bit-exact vs ref
                bits |= ((uint64_t)((j > r) && (iou > D_IOU_THR))) << kk;
            }
        }
        M[((size_t)b * 1024 + r) * 16 + w] = bits;
        if (w == rb) D[((size_t)b * 16 + rb) * 64 + rl] = bits;
    }
}

// ---------------- S3: LDS-staged group scan (wave 0 resolves, waves 1-3 load) ----

__global__ __launch_bounds__(256) void k_scan(
    const uint64_t* __restrict__ M, const uint64_t* __restrict__ D,
    const uint64_t* __restrict__ keepw,
    const float* __restrict__ outs, const float* __restrict__ outc,
    const float* __restrict__ outb, float* __restrict__ out)
{
    __shared__ uint64_t buf[2][1024];   // double-buffered group of 64 M rows (8 KB each)
    __shared__ uint64_t kl[16];
    int b = blockIdx.x;
    int tid = threadIdx.x;
    const uint64_t* Mb = M + (size_t)b * 1024 * 16;

    // stage group 0
    for (int t = tid; t < 1024; t += 256) buf[0][t] = Mb[t];

    uint64_t Dg[16];
    uint64_t kw = 0;
    int lane = tid & 63;
    int kp = lane >> 4, w = lane & 15;
    if (tid < 64) {
#pragma unroll
        for (int g = 0; g < 16; ++g) Dg[g] = D[((size_t)b * 16 + g) * 64 + lane];
        kw = keepw[(size_t)b * 16 + w];   // replicated x4 across kp
    }
    __syncthreads();

#pragma unroll 16
    for (int G = 0; G < 16; ++G) {
        int cb = G & 1;
        // prefetch next group into the other buffer (all 256 threads)
        if (G < 15) {
            for (int t = tid; t < 1024; t += 256)
                buf[cb ^ 1][t] = Mb[(size_t)(G + 1) * 1024 + t];
        }
        if (tid < 64) {
            // issue LDS reads early; latency hides under the scalar resolution
            uint64_t cur[16];
#pragma unroll
            for (int q = 0; q < 16; ++q) cur[q] = buf[cb][(4 * q + kp) * 16 + w];

            // intra-group greedy resolution (uniform scalar, visits alive bits only)
            uint64_t kg = rl64(kw, G);      // lane G (kp=0, w=G) holds word G
            uint64_t dgl = Dg[G];
            uint64_t rem = kg, alive = 0;
            while (rem) {
                int kk = __builtin_ctzll(rem);
                alive |= 1ull << kk;
                rem &= ~rl64(dgl, kk);      // D bits are strictly > kk
                rem &= rem - 1ull;          // clear bit kk
            }

            // branchless apply of alive rows to all 16 words
            uint64_t acc = ~0ull;
#pragma unroll
            for (int q = 0; q < 16; ++q) {
                uint64_t t = (alive >> (4 * q + kp)) & 1ull;
                acc &= ~(cur[q] & (0ull - t));
            }
            acc &= __shfl_xor(acc, 16, 64);
            acc &= __shfl_xor(acc, 32, 64);
            kw &= acc;   // word G becomes `alive`; words < G untouched (M only has j>i bits)
        }
        __syncthreads();   // next buffer staged; current buffer consumed
    }

    if (tid < 16) kl[tid] = kw;
    __syncthreads();

    for (int j = tid; j < KTOP; j += 256) {
        bool kp2 = (kl[j >> 6] >> (j & 63)) & 1ull;
        size_t ix = (size_t)b * 1024 + j;
        out[(size_t)b * KTOP + j] = kp2 ? outs[ix] : 0.0f;
        out[(size_t)NB * KTOP + (size_t)b * KTOP + j] = kp2 ? outc[ix] : 0.0f;
        float4 bb = kp2 ? ((const float4*)outb)[ix] : make_float4(0.f, 0.f, 0.f, 0.f);
        ((float4*)(out + 2 * (size_t)NB * KTOP))[(size_t)b * KTOP + j] = bb;
    }
}

// ---------------- launch ----------------

extern "C" void kernel_launch(void* const* d_in, const int* in_sizes, int n_in,
                              void* d_out, int out_size, void* d_ws, size_t ws_size,
                              hipStream_t stream) {
    const float* cls[5];
    const float* cnt[5];
    const float* reg[5];
    for (int i = 0; i < 5; ++i) {
        cls[i] = (const float*)d_in[i];
        cnt[i] = (const float*)d_in[5 + i];
        reg[i] = (const float*)d_in[10 + i];
    }
    float* out = (float*)d_out;

    // ws layout (bytes); M reuses the packed region (packed dead after k_select)
    char* ws = (char*)d_ws;
    uint64_t* packed  = (uint64_t*)(ws + 0);          // 8*16384*8     = 1,048,576
    uint64_t* M       = (uint64_t*)(ws + 0);          // 8*1024*16*8   = 1,048,576 (reuse)
    int*      classes = (int*)     (ws + 1048576);    // 8*13343*4     =   426,976
    uint64_t* tkeys   = (uint64_t*)(ws + 1475552);    // 8*1024*8      =    65,536
    uint64_t* D       = (uint64_t*)(ws + 1541088);    // 8*16*64*8     =    65,536
    uint64_t* keepw   = (uint64_t*)(ws + 1606624);    // 8*16*8        =     1,024
    float*    outs    = (float*)   (ws + 1607648);    // 8*1024*4      =    32,768
    float*    outc    = (float*)   (ws + 1640416);    // 8*1024*4      =    32,768
    float*    outb    = (float*)   (ws + 1673184);    // 8*1024*16     =   131,072

    k_scores<<<(NB * PPAD) / 256, 256, 0, stream>>>(
        cls[0], cls[1], cls[2], cls[3], cls[4],
        cnt[0], cnt[1], cnt[2], cnt[3], cnt[4],
        packed, classes);

    k_select<<<NB, 512, 0, stream>>>(packed, tkeys);

    k_boxmask<<<NB * 16, 256, 0, stream>>>(tkeys, classes,
                                           reg[0], reg[1], reg[2], reg[3], reg[4],
                                           outs, outc, outb, keepw, M, D);

    k_scan<<<NB, 64 * 4, 0, stream>>>(M, D, keepw, outs, outc, outb, out);
}

// Round 5
// 149.052 us; speedup vs baseline: 1.1521x; 1.1521x over previous
//
#include <hip/hip_runtime.h>
#include <math.h>
#include <stdint.h>

#define NB 8
#define P_TOTAL 13343
#define NCLS 80
#define KTOP 1000
#define PPAD 16384
#define D_SCORE_THR 0.05
#define D_IOU_THR 0.6

// ---------------- helpers ----------------

__device__ __forceinline__ double sig64(double x) {
    if (x >= 0.0) {
        double e = exp(-x);
        return 1.0 / (1.0 + e);
    } else {
        double e = exp(x);
        return e / (1.0 + e);
    }
}

// key = score bits (top 50) | (0x3FFF - idx): descending sort => score desc, idx asc
__device__ __forceinline__ uint64_t pack_key(double s, int p) {
    uint64_t b = (uint64_t)__double_as_longlong(s);
    return (b & ~0x3FFFull) | (uint64_t)(0x3FFF - p);
}

__device__ __forceinline__ uint64_t rl64(uint64_t v, int l) {
    uint32_t lo = (uint32_t)__builtin_amdgcn_readlane((int)(uint32_t)v, l);
    uint32_t hi = (uint32_t)__builtin_amdgcn_readlane((int)(uint32_t)(v >> 32), l);
    return ((uint64_t)hi << 32) | lo;
}

// Bitonic sort (descending) on uint64 keys in LDS. n power of two.
__device__ void bitonic_u64(uint64_t* sk, int n, int tid, int nthr) {
    for (int k2 = 2; k2 <= n; k2 <<= 1) {
        for (int j = k2 >> 1; j > 0; j >>= 1) {
            for (int t = tid; t < (n >> 1); t += nthr) {
                int i = ((t & ~(j - 1)) << 1) | (t & (j - 1));
                int l = i | j;
                uint64_t a = sk[i], b = sk[l];
                bool prec = (a > b);
                bool desc = ((i & k2) == 0);
                if (prec != desc) { sk[i] = b; sk[l] = a; }
            }
            __syncthreads();
        }
    }
}

// ---------------- S0: scores/classes -> packed keys ----------------

__global__ __launch_bounds__(256) void k_scores(
    const float* __restrict__ c0, const float* __restrict__ c1, const float* __restrict__ c2,
    const float* __restrict__ c3, const float* __restrict__ c4,
    const float* __restrict__ n0, const float* __restrict__ n1, const float* __restrict__ n2,
    const float* __restrict__ n3, const float* __restrict__ n4,
    uint64_t* __restrict__ packed, int* __restrict__ classes)
{
    int gid = blockIdx.x * 256 + threadIdx.x;
    if (gid >= NB * PPAD) return;
    int b = gid >> 14;
    int p = gid & (PPAD - 1);
    if (p >= P_TOTAL) { packed[gid] = 0; return; }

    int base, hw;
    const float* cls;
    const float* cnt;
    if (p < 10000)      { base = 0;     hw = 10000; cls = c0; cnt = n0; }
    else if (p < 12500) { base = 10000; hw = 2500;  cls = c1; cnt = n1; }
    else if (p < 13125) { base = 12500; hw = 625;   cls = c2; cnt = n2; }
    else if (p < 13294) { base = 13125; hw = 169;   cls = c3; cnt = n3; }
    else                { base = 13294; hw = 49;    cls = c4; cnt = n4; }
    int yx = p - base;

    const float* cp = cls + (size_t)b * NCLS * hw + yx;
    float m = -3.4e38f;
    int am = 0;
    for (int c = 0; c < NCLS; ++c) {
        float v = cp[(size_t)c * hw];
        if (v > m) { m = v; am = c; }   // first max, matches jnp.argmax
    }
    float cv = cnt[(size_t)b * hw + yx];
    double s = sqrt(sig64((double)m) * sig64((double)cv));

    packed[gid] = pack_key(s, p);
    classes[(size_t)b * P_TOTAL + p] = am + 1;
}

// ---------------- S1: value-histogram select + sort -> top 1024 ----------------

__global__ __launch_bounds__(512) void k_select(
    const uint64_t* __restrict__ packed, uint64_t* __restrict__ tkeys)
{
    __shared__ uint32_t hist[2048];
    __shared__ uint64_t cand[2048];
    __shared__ uint32_t chs[64];
    __shared__ int sB, sC1, sB2, sCnt;
    int b = blockIdx.x;
    int tid = threadIdx.x;
    const uint64_t* pk = packed + (size_t)b * PPAD;

    for (int t = tid; t < 2048; t += 512) hist[t] = 0;
    __syncthreads();

    // pass 1: coarse 2048-bin VALUE histogram (well-spread for s in [0,1])
    for (int t = tid; t < PPAD; t += 512) {
        double s = __longlong_as_double((long long)(pk[t] & ~0x3FFFull));
        int bin = (int)(s * 2048.0);
        bin = bin < 0 ? 0 : (bin > 2047 ? 2047 : bin);
        atomicAdd(&hist[bin], 1u);
    }
    __syncthreads();
    if (tid < 64) {
        uint32_t ssum = 0;
        for (int i = 0; i < 32; ++i) ssum += hist[tid * 32 + i];
        chs[tid] = ssum;
    }
    __syncthreads();
    if (tid == 0) {
        int acc = 0, c = 63;
        for (; c > 0; --c) { if (acc + (int)chs[c] >= 1024) break; acc += (int)chs[c]; }
        int bfound = c * 32;
        for (int bb = c * 32 + 31; bb >= c * 32; --bb) {
            if (acc + (int)hist[bb] >= 1024) { bfound = bb; break; }
            acc += (int)hist[bb];
        }
        sB = bfound; sC1 = acc;   // acc = count of keys with bin > sB
    }
    __syncthreads();
    int B = sB;
    for (int t = tid; t < 2048; t += 512) hist[t] = 0;
    __syncthreads();

    // pass 2: refine crossing bin into 2048 sub-bins
    for (int t = tid; t < PPAD; t += 512) {
        double s = __longlong_as_double((long long)(pk[t] & ~0x3FFFull));
        int bin = (int)(s * 2048.0);
        bin = bin < 0 ? 0 : (bin > 2047 ? 2047 : bin);
        if (bin == B) {
            int sub = (int)(s * 4194304.0) - B * 2048;
            sub = sub < 0 ? 0 : (sub > 2047 ? 2047 : sub);
            atomicAdd(&hist[sub], 1u);
        }
    }
    __syncthreads();
    if (tid < 64) {
        uint32_t ssum = 0;
        for (int i = 0; i < 32; ++i) ssum += hist[tid * 32 + i];
        chs[tid] = ssum;
    }
    __syncthreads();
    if (tid == 0) {
        int acc = sC1, c = 63;
        for (; c > 0; --c) { if (acc + (int)chs[c] >= 1024) break; acc += (int)chs[c]; }
        int bfound = c * 32;
        for (int bb = c * 32 + 31; bb >= c * 32; --bb) {
            if (acc + (int)hist[bb] >= 1024) { bfound = bb; break; }
            acc += (int)hist[bb];
        }
        sB2 = bfound;
        sCnt = 0;
    }
    __syncthreads();
    int B2 = sB2;

    // pass 3: compact candidates (exact-rank superset; sort canonicalizes)
    for (int t = tid; t < PPAD; t += 512) {
        uint64_t key = pk[t];
        double s = __longlong_as_double((long long)(key & ~0x3FFFull));
        int bin = (int)(s * 2048.0);
        bin = bin < 0 ? 0 : (bin > 2047 ? 2047 : bin);
        bool pred = false;
        if (bin > B) pred = true;
        else if (bin == B) {
            int sub = (int)(s * 4194304.0) - B * 2048;
            sub = sub < 0 ? 0 : (sub > 2047 ? 2047 : sub);
            pred = (sub >= B2);
        }
        if (pred) {
            int slot = atomicAdd(&sCnt, 1);
            if (slot < 2048) cand[slot] = key;
        }
    }
    __syncthreads();
    int cnt = sCnt < 2048 ? sCnt : 2048;

    if (cnt <= 1024) {
        for (int t = tid; t < 1024; t += 512) if (t >= cnt) cand[t] = 0;
        __syncthreads();
        bitonic_u64(cand, 1024, tid, 512);
    } else {
        for (int t = tid; t < 2048; t += 512) if (t >= cnt) cand[t] = 0;
        __syncthreads();
        bitonic_u64(cand, 2048, tid, 512);
    }

    for (int t = tid; t < 1024; t += 512)
        tkeys[(size_t)b * 1024 + t] = cand[t];
}

// ---------------- S2: fused box gather + offsets + mask matrix ----------------

__global__ __launch_bounds__(256) void k_boxmask(
    const uint64_t* __restrict__ tkeys, const int* __restrict__ classes,
    const float* __restrict__ r0, const float* __restrict__ r1, const float* __restrict__ r2,
    const float* __restrict__ r3, const float* __restrict__ r4,
    float* __restrict__ outs, float* __restrict__ outc, float* __restrict__ outb,
    uint64_t* __restrict__ keepw,
    uint64_t* __restrict__ M, uint64_t* __restrict__ D)
{
    __shared__ double lx1[1024], ly1[1024], lx2[1024], ly2[1024], lar[1024];
    __shared__ double red[256];
    int bid = blockIdx.x;
    int b = bid >> 4, rb = bid & 15;
    int tid = threadIdx.x;

    double vx1[4], vy1[4], vx2[4], vy2[4], sc[4];
    int cls_[4];
    double lmax = -1e300;

#pragma unroll
    for (int k = 0; k < 4; ++k) {
        int j = tid + k * 256;
        uint64_t key = tkeys[(size_t)b * 1024 + j];
        int idx = 0x3FFF - (int)(key & 0x3FFF);
        idx = idx < 0 ? 0 : (idx > P_TOTAL - 1 ? P_TOTAL - 1 : idx);
        double s = __longlong_as_double((long long)(key & ~0x3FFFull));

        int base, w, hw, st;
        const float* reg;
        if (idx < 10000)      { base = 0;     w = 100; hw = 10000; st = 8;   reg = r0; }
        else if (idx < 12500) { base = 10000; w = 50;  hw = 2500;  st = 16;  reg = r1; }
        else if (idx < 13125) { base = 12500; w = 25;  hw = 625;   st = 32;  reg = r2; }
        else if (idx < 13294) { base = 13125; w = 13;  hw = 169;   st = 64;  reg = r3; }
        else                  { base = 13294; w = 7;   hw = 49;    st = 128; reg = r4; }
        int yx = idx - base;
        int y = yx / w;
        int x = yx - y * w;
        double sx = (double)(x * st + st / 2);
        double sy = (double)(y * st + st / 2);
        const float* rp = reg + (size_t)b * 4 * hw + yx;
        double x1 = sx - (double)rp[0];
        double y1 = sy - (double)rp[hw];
        double x2 = sx + (double)rp[2 * (size_t)hw];
        double y2 = sy + (double)rp[3 * (size_t)hw];
        int cv = classes[(size_t)b * P_TOTAL + idx];

        bool valid = (j < KTOP) && (s >= D_SCORE_THR);
        if (j < KTOP) {
            lmax = fmax(lmax, valid ? x1 : 0.0);
            lmax = fmax(lmax, valid ? y1 : 0.0);
            lmax = fmax(lmax, valid ? x2 : 0.0);
            lmax = fmax(lmax, valid ? y2 : 0.0);
        }
        vx1[k] = x1; vy1[k] = y1; vx2[k] = x2; vy2[k] = y2;
        sc[k] = s; cls_[k] = cv;

        uint64_t bal = __ballot(valid);
        if (rb == 0 && (tid & 63) == 0) keepw[(size_t)b * 16 + (tid >> 6) + 4 * k] = bal;
    }

    red[tid] = lmax;
    __syncthreads();
    for (int s2 = 128; s2 > 0; s2 >>= 1) {
        if (tid < s2) red[tid] = fmax(red[tid], red[tid + s2]);
        __syncthreads();
    }
    double offscale = red[0] + 1.0;
    __syncthreads();

#pragma unroll
    for (int k = 0; k < 4; ++k) {
        int j = tid + k * 256;
        double o = (double)cls_[k] * offscale;
        double ox1 = vx1[k] + o, oy1 = vy1[k] + o;
        double ox2 = vx2[k] + o, oy2 = vy2[k] + o;
        lx1[j] = ox1; ly1[j] = oy1; lx2[j] = ox2; ly2[j] = oy2;
        lar[j] = (ox2 - ox1 + 1.0) * (oy2 - oy1 + 1.0);
        if (rb == 0 && j < KTOP) {
            size_t ix = (size_t)b * 1024 + j;
            outs[ix] = (float)sc[k];
            outc[ix] = (float)cls_[k];
            ((float4*)outb)[ix] = make_float4((float)vx1[k], (float)vy1[k],
                                              (float)vx2[k], (float)vy2[k]);
        }
    }
    __syncthreads();

    int rl = tid >> 2;          // 0..63
    int wq = tid & 3;
    int r = rb * 64 + rl;
    double rx1 = lx1[r], ry1 = ly1[r], rx2 = lx2[r], ry2 = ly2[r], ra = lar[r];

#pragma unroll
    for (int ww = 0; ww < 4; ++ww) {
        int w = ww * 4 + wq;
        uint64_t bits = 0;
        if (w * 64 + 63 > r) {
            for (int kk = 0; kk < 64; ++kk) {
                int j = w * 64 + kk;
                double xmn = fmax(lx1[j], rx1);
                double ymn = fmax(ly1[j], ry1);
                double xmx = fmin(lx2[j], rx2);
                double ymx = fmin(ly2[j], ry2);
                double iw = xmx - xmn; iw = iw < 0.0 ? 0.0 : iw;
                double ih = ymx - ymn; ih = ih < 0.0 ? 0.0 : ih;
                double inter = iw * ih;
                double iou = inter / (ra + lar[j] - inter);   // f64 div: bit-exact vs ref
                bits |= ((uint64_t)((j > r) && (iou > D_IOU_THR))) << kk;
            }
        }
        M[((size_t)b * 1024 + r) * 16 + w] = bits;
        if (w == rb) D[((size_t)b * 16 + rb) * 64 + rl] = bits;
    }
}

// ---------------- S3: one-wave scan, named register banks (no arrays, no LDS) ----

#define LOAD_BANK(A, G)                                                        \
    A##0  = Mb[((size_t)(G) * 64 +  0 + p) * 16 + w];                          \
    A##1  = Mb[((size_t)(G) * 64 +  4 + p) * 16 + w];                          \
    A##2  = Mb[((size_t)(G) * 64 +  8 + p) * 16 + w];                          \
    A##3  = Mb[((size_t)(G) * 64 + 12 + p) * 16 + w];                          \
    A##4  = Mb[((size_t)(G) * 64 + 16 + p) * 16 + w];                          \
    A##5  = Mb[((size_t)(G) * 64 + 20 + p) * 16 + w];                          \
    A##6  = Mb[((size_t)(G) * 64 + 24 + p) * 16 + w];                          \
    A##7  = Mb[((size_t)(G) * 64 + 28 + p) * 16 + w];                          \
    A##8  = Mb[((size_t)(G) * 64 + 32 + p) * 16 + w];                          \
    A##9  = Mb[((size_t)(G) * 64 + 36 + p) * 16 + w];                          \
    A##10 = Mb[((size_t)(G) * 64 + 40 + p) * 16 + w];                          \
    A##11 = Mb[((size_t)(G) * 64 + 44 + p) * 16 + w];                          \
    A##12 = Mb[((size_t)(G) * 64 + 48 + p) * 16 + w];                          \
    A##13 = Mb[((size_t)(G) * 64 + 52 + p) * 16 + w];                          \
    A##14 = Mb[((size_t)(G) * 64 + 56 + p) * 16 + w];                          \
    A##15 = Mb[((size_t)(G) * 64 + 60 + p) * 16 + w];

#define APPLY_Q(A, q)                                                          \
    {                                                                          \
        uint64_t t_ = (alive >> (4 * (q) + p)) & 1ull;                         \
        acc &= ~(A##q & (0ull - t_));                                          \
    }

#define APPLY_BANK(A)                                                          \
    APPLY_Q(A, 0)  APPLY_Q(A, 1)  APPLY_Q(A, 2)  APPLY_Q(A, 3)                 \
    APPLY_Q(A, 4)  APPLY_Q(A, 5)  APPLY_Q(A, 6)  APPLY_Q(A, 7)                 \
    APPLY_Q(A, 8)  APPLY_Q(A, 9)  APPLY_Q(A, 10) APPLY_Q(A, 11)                \
    APPLY_Q(A, 12) APPLY_Q(A, 13) APPLY_Q(A, 14) APPLY_Q(A, 15)

#define STEP(G, CUR, NXT)                                                      \
    {                                                                          \
        if ((G) < 15) {                                                        \
            LOAD_BANK(NXT, (G) + 1)                                            \
            dgn = Dp[(size_t)((G) + 1) * 64 + lane];                           \
        }                                                                      \
        uint64_t kg = rl64(kw, (G));                                           \
        uint64_t rem = kg, alive = 0;                                          \
        while (rem) {                                                          \
            int kk = __builtin_ctzll(rem);                                     \
            alive |= 1ull << kk;                                               \
            rem &= ~rl64(dg, kk);                                              \
            rem &= rem - 1ull;                                                 \
        }                                                                      \
        uint64_t acc = ~0ull;                                                  \
        APPLY_BANK(CUR)                                                        \
        acc &= __shfl_xor(acc, 16, 64);                                        \
        acc &= __shfl_xor(acc, 32, 64);                                        \
        kw &= acc;                                                             \
        dg = dgn;                                                              \
    }

__global__ __launch_bounds__(64, 1) void k_scan(
    const uint64_t* __restrict__ M, const uint64_t* __restrict__ D,
    const uint64_t* __restrict__ keepw,
    const float* __restrict__ outs, const float* __restrict__ outc,
    const float* __restrict__ outb, float* __restrict__ out)
{
    int b = blockIdx.x;
    int lane = threadIdx.x;          // one wave
    int p = (lane >> 4) & 3;         // replica 0..3
    int w = lane & 15;               // word index
    const uint64_t* Mb = M + (size_t)b * 1024 * 16;
    const uint64_t* Dp = D + (size_t)b * 1024;

    uint64_t kw = keepw[(size_t)b * 16 + w];   // word w, replicated x4
    uint64_t dg = Dp[lane];                    // D row for group 0
    uint64_t dgn = 0;

    uint64_t A0,A1,A2,A3,A4,A5,A6,A7,A8,A9,A10,A11,A12,A13,A14,A15;
    uint64_t B0,B1,B2,B3,B4,B5,B6,B7,B8,B9,B10,B11,B12,B13,B14,B15;

    LOAD_BANK(A, 0)

    STEP(0,  A, B)  STEP(1,  B, A)  STEP(2,  A, B)  STEP(3,  B, A)
    STEP(4,  A, B)  STEP(5,  B, A)  STEP(6,  A, B)  STEP(7,  B, A)
    STEP(8,  A, B)  STEP(9,  B, A)  STEP(10, A, B)  STEP(11, B, A)
    STEP(12, A, B)  STEP(13, B, A)  STEP(14, A, B)  STEP(15, B, A)

    // outputs: keep word for row-block t is uniform (readlane), bit = lane
#pragma unroll
    for (int t = 0; t < 16; ++t) {
        int j = t * 64 + lane;
        uint64_t kwt = rl64(kw, t);
        bool kp = (kwt >> lane) & 1ull;
        if (j < KTOP) {
            size_t ix = (size_t)b * 1024 + j;
            out[(size_t)b * KTOP + j] = kp ? outs[ix] : 0.0f;
            out[(size_t)NB * KTOP + (size_t)b * KTOP + j] = kp ? outc[ix] : 0.0f;
            float4 bb = kp ? ((const float4*)outb)[ix] : make_float4(0.f, 0.f, 0.f, 0.f);
            ((float4*)(out + 2 * (size_t)NB * KTOP))[(size_t)b * KTOP + j] = bb;
        }
    }
}

// ---------------- launch ----------------

extern "C" void kernel_launch(void* const* d_in, const int* in_sizes, int n_in,
                              void* d_out, int out_size, void* d_ws, size_t ws_size,
                              hipStream_t stream) {
    const float* cls[5];
    const float* cnt[5];
    const float* reg[5];
    for (int i = 0; i < 5; ++i) {
        cls[i] = (const float*)d_in[i];
        cnt[i] = (const float*)d_in[5 + i];
        reg[i] = (const float*)d_in[10 + i];
    }
    float* out = (float*)d_out;

    // ws layout (bytes); M reuses the packed region (packed dead after k_select)
    char* ws = (char*)d_ws;
    uint64_t* packed  = (uint64_t*)(ws + 0);          // 8*16384*8     = 1,048,576
    uint64_t* M       = (uint64_t*)(ws + 0);          // 8*1024*16*8   = 1,048,576 (reuse)
    int*      classes = (int*)     (ws + 1048576);    // 8*13343*4     =   426,976
    uint64_t* tkeys   = (uint64_t*)(ws + 1475552);    // 8*1024*8      =    65,536
    uint64_t* D       = (uint64_t*)(ws + 1541088);    // 8*16*64*8     =    65,536
    uint64_t* keepw   = (uint64_t*)(ws + 1606624);    // 8*16*8        =     1,024
    float*    outs    = (float*)   (ws + 1607648);    // 8*1024*4      =    32,768
    float*    outc    = (float*)   (ws + 1640416);    // 8*1024*4      =    32,768
    float*    outb    = (float*)   (ws + 1673184);    // 8*1024*16     =   131,072

    k_scores<<<(NB * PPAD) / 256, 256, 0, stream>>>(
        cls[0], cls[1], cls[2], cls[3], cls[4],
        cnt[0], cnt[1], cnt[2], cnt[3], cnt[4],
        packed, classes);

    k_select<<<NB, 512, 0, stream>>>(packed, tkeys);

    k_boxmask<<<NB * 16, 256, 0, stream>>>(tkeys, classes,
                                           reg[0], reg[1], reg[2], reg[3], reg[4],
                                           outs, outc, outb, keepw, M, D);

    k_scan<<<NB, 64, 0, stream>>>(M, D, keepw, outs, outc, outb, out);
}

// Round 6
// 103.553 us; speedup vs baseline: 1.6583x; 1.4394x over previous
//
#include <hip/hip_runtime.h>
#include <math.h>
#include <stdint.h>

#define NB 8
#define P_TOTAL 13343
#define NCLS 80
#define KTOP 1000
#define PPAD 16384
#define D_SCORE_THR 0.05
#define D_IOU_THR 0.6

// ---------------- helpers ----------------

__device__ __forceinline__ double sig64(double x) {
    if (x >= 0.0) {
        double e = exp(-x);
        return 1.0 / (1.0 + e);
    } else {
        double e = exp(x);
        return e / (1.0 + e);
    }
}

// key = score bits (top 50) | (0x3FFF - idx): descending sort => score desc, idx asc
__device__ __forceinline__ uint64_t pack_key(double s, int p) {
    uint64_t b = (uint64_t)__double_as_longlong(s);
    return (b & ~0x3FFFull) | (uint64_t)(0x3FFF - p);
}

__device__ __forceinline__ uint64_t rl64(uint64_t v, int l) {
    uint32_t lo = (uint32_t)__builtin_amdgcn_readlane((int)(uint32_t)v, l);
    uint32_t hi = (uint32_t)__builtin_amdgcn_readlane((int)(uint32_t)(v >> 32), l);
    return ((uint64_t)hi << 32) | lo;
}

// Bitonic sort (descending) on uint64 keys in LDS. n power of two.
__device__ void bitonic_u64(uint64_t* sk, int n, int tid, int nthr) {
    for (int k2 = 2; k2 <= n; k2 <<= 1) {
        for (int j = k2 >> 1; j > 0; j >>= 1) {
            for (int t = tid; t < (n >> 1); t += nthr) {
                int i = ((t & ~(j - 1)) << 1) | (t & (j - 1));
                int l = i | j;
                uint64_t a = sk[i], b = sk[l];
                bool prec = (a > b);
                bool desc = ((i & k2) == 0);
                if (prec != desc) { sk[i] = b; sk[l] = a; }
            }
            __syncthreads();
        }
    }
}

// ---------------- S0: scores/classes -> packed keys ----------------

__global__ __launch_bounds__(256) void k_scores(
    const float* __restrict__ c0, const float* __restrict__ c1, const float* __restrict__ c2,
    const float* __restrict__ c3, const float* __restrict__ c4,
    const float* __restrict__ n0, const float* __restrict__ n1, const float* __restrict__ n2,
    const float* __restrict__ n3, const float* __restrict__ n4,
    uint64_t* __restrict__ packed, int* __restrict__ classes)
{
    int gid = blockIdx.x * 256 + threadIdx.x;
    if (gid >= NB * PPAD) return;
    int b = gid >> 14;
    int p = gid & (PPAD - 1);
    if (p >= P_TOTAL) { packed[gid] = 0; return; }

    int base, hw;
    const float* cls;
    const float* cnt;
    if (p < 10000)      { base = 0;     hw = 10000; cls = c0; cnt = n0; }
    else if (p < 12500) { base = 10000; hw = 2500;  cls = c1; cnt = n1; }
    else if (p < 13125) { base = 12500; hw = 625;   cls = c2; cnt = n2; }
    else if (p < 13294) { base = 13125; hw = 169;   cls = c3; cnt = n3; }
    else                { base = 13294; hw = 49;    cls = c4; cnt = n4; }
    int yx = p - base;

    const float* cp = cls + (size_t)b * NCLS * hw + yx;
    float m = -3.4e38f;
    int am = 0;
    for (int c = 0; c < NCLS; ++c) {
        float v = cp[(size_t)c * hw];
        if (v > m) { m = v; am = c; }   // first max, matches jnp.argmax
    }
    float cv = cnt[(size_t)b * hw + yx];
    double s = sqrt(sig64((double)m) * sig64((double)cv));

    packed[gid] = pack_key(s, p);
    classes[(size_t)b * P_TOTAL + p] = am + 1;
}

// ---------------- S1: value-histogram select + sort -> top 1024 ----------------

__global__ __launch_bounds__(512) void k_select(
    const uint64_t* __restrict__ packed, uint64_t* __restrict__ tkeys)
{
    __shared__ uint32_t hist[2048];
    __shared__ uint64_t cand[2048];
    __shared__ uint32_t chs[64];
    __shared__ int sB, sC1, sB2, sCnt;
    int b = blockIdx.x;
    int tid = threadIdx.x;
    const uint64_t* pk = packed + (size_t)b * PPAD;

    for (int t = tid; t < 2048; t += 512) hist[t] = 0;
    __syncthreads();

    // pass 1: coarse 2048-bin VALUE histogram (well-spread for s in [0,1])
    for (int t = tid; t < PPAD; t += 512) {
        double s = __longlong_as_double((long long)(pk[t] & ~0x3FFFull));
        int bin = (int)(s * 2048.0);
        bin = bin < 0 ? 0 : (bin > 2047 ? 2047 : bin);
        atomicAdd(&hist[bin], 1u);
    }
    __syncthreads();
    if (tid < 64) {
        uint32_t ssum = 0;
        for (int i = 0; i < 32; ++i) ssum += hist[tid * 32 + i];
        chs[tid] = ssum;
    }
    __syncthreads();
    if (tid == 0) {
        int acc = 0, c = 63;
        for (; c > 0; --c) { if (acc + (int)chs[c] >= 1024) break; acc += (int)chs[c]; }
        int bfound = c * 32;
        for (int bb = c * 32 + 31; bb >= c * 32; --bb) {
            if (acc + (int)hist[bb] >= 1024) { bfound = bb; break; }
            acc += (int)hist[bb];
        }
        sB = bfound; sC1 = acc;   // acc = count of keys with bin > sB
    }
    __syncthreads();
    int B = sB;
    for (int t = tid; t < 2048; t += 512) hist[t] = 0;
    __syncthreads();

    // pass 2: refine crossing bin into 2048 sub-bins
    for (int t = tid; t < PPAD; t += 512) {
        double s = __longlong_as_double((long long)(pk[t] & ~0x3FFFull));
        int bin = (int)(s * 2048.0);
        bin = bin < 0 ? 0 : (bin > 2047 ? 2047 : bin);
        if (bin == B) {
            int sub = (int)(s * 4194304.0) - B * 2048;
            sub = sub < 0 ? 0 : (sub > 2047 ? 2047 : sub);
            atomicAdd(&hist[sub], 1u);
        }
    }
    __syncthreads();
    if (tid < 64) {
        uint32_t ssum = 0;
        for (int i = 0; i < 32; ++i) ssum += hist[tid * 32 + i];
        chs[tid] = ssum;
    }
    __syncthreads();
    if (tid == 0) {
        int acc = sC1, c = 63;
        for (; c > 0; --c) { if (acc + (int)chs[c] >= 1024) break; acc += (int)chs[c]; }
        int bfound = c * 32;
        for (int bb = c * 32 + 31; bb >= c * 32; --bb) {
            if (acc + (int)hist[bb] >= 1024) { bfound = bb; break; }
            acc += (int)hist[bb];
        }
        sB2 = bfound;
        sCnt = 0;
    }
    __syncthreads();
    int B2 = sB2;

    // pass 3: compact candidates (exact-rank superset; sort canonicalizes)
    for (int t = tid; t < PPAD; t += 512) {
        uint64_t key = pk[t];
        double s = __longlong_as_double((long long)(key & ~0x3FFFull));
        int bin = (int)(s * 2048.0);
        bin = bin < 0 ? 0 : (bin > 2047 ? 2047 : bin);
        bool pred = false;
        if (bin > B) pred = true;
        else if (bin == B) {
            int sub = (int)(s * 4194304.0) - B * 2048;
            sub = sub < 0 ? 0 : (sub > 2047 ? 2047 : sub);
            pred = (sub >= B2);
        }
        if (pred) {
            int slot = atomicAdd(&sCnt, 1);
            if (slot < 2048) cand[slot] = key;
        }
    }
    __syncthreads();
    int cnt = sCnt < 2048 ? sCnt : 2048;

    if (cnt <= 1024) {
        for (int t = tid; t < 1024; t += 512) if (t >= cnt) cand[t] = 0;
        __syncthreads();
        bitonic_u64(cand, 1024, tid, 512);
    } else {
        for (int t = tid; t < 2048; t += 512) if (t >= cnt) cand[t] = 0;
        __syncthreads();
        bitonic_u64(cand, 2048, tid, 512);
    }

    for (int t = tid; t < 1024; t += 512)
        tkeys[(size_t)b * 1024 + t] = cand[t];
}

// ---------------- S2: fused box gather + offsets + mask matrix + row flags ------

__global__ __launch_bounds__(256) void k_boxmask(
    const uint64_t* __restrict__ tkeys, const int* __restrict__ classes,
    const float* __restrict__ r0, const float* __restrict__ r1, const float* __restrict__ r2,
    const float* __restrict__ r3, const float* __restrict__ r4,
    float* __restrict__ outs, float* __restrict__ outc, float* __restrict__ outb,
    uint64_t* __restrict__ keepw,
    uint64_t* __restrict__ M, uint64_t* __restrict__ D,
    uint32_t* __restrict__ Rnz)
{
    __shared__ double lx1[1024], ly1[1024], lx2[1024], ly2[1024], lar[1024];
    __shared__ double red[256];
    int bid = blockIdx.x;
    int b = bid >> 4, rb = bid & 15;
    int tid = threadIdx.x;

    double vx1[4], vy1[4], vx2[4], vy2[4], sc[4];
    int cls_[4];
    double lmax = -1e300;

#pragma unroll
    for (int k = 0; k < 4; ++k) {
        int j = tid + k * 256;
        uint64_t key = tkeys[(size_t)b * 1024 + j];
        int idx = 0x3FFF - (int)(key & 0x3FFF);
        idx = idx < 0 ? 0 : (idx > P_TOTAL - 1 ? P_TOTAL - 1 : idx);
        double s = __longlong_as_double((long long)(key & ~0x3FFFull));

        int base, w, hw, st;
        const float* reg;
        if (idx < 10000)      { base = 0;     w = 100; hw = 10000; st = 8;   reg = r0; }
        else if (idx < 12500) { base = 10000; w = 50;  hw = 2500;  st = 16;  reg = r1; }
        else if (idx < 13125) { base = 12500; w = 25;  hw = 625;   st = 32;  reg = r2; }
        else if (idx < 13294) { base = 13125; w = 13;  hw = 169;   st = 64;  reg = r3; }
        else                  { base = 13294; w = 7;   hw = 49;    st = 128; reg = r4; }
        int yx = idx - base;
        int y = yx / w;
        int x = yx - y * w;
        double sx = (double)(x * st + st / 2);
        double sy = (double)(y * st + st / 2);
        const float* rp = reg + (size_t)b * 4 * hw + yx;
        double x1 = sx - (double)rp[0];
        double y1 = sy - (double)rp[hw];
        double x2 = sx + (double)rp[2 * (size_t)hw];
        double y2 = sy + (double)rp[3 * (size_t)hw];
        int cv = classes[(size_t)b * P_TOTAL + idx];

        bool valid = (j < KTOP) && (s >= D_SCORE_THR);
        if (j < KTOP) {
            lmax = fmax(lmax, valid ? x1 : 0.0);
            lmax = fmax(lmax, valid ? y1 : 0.0);
            lmax = fmax(lmax, valid ? x2 : 0.0);
            lmax = fmax(lmax, valid ? y2 : 0.0);
        }
        vx1[k] = x1; vy1[k] = y1; vx2[k] = x2; vy2[k] = y2;
        sc[k] = s; cls_[k] = cv;

        uint64_t bal = __ballot(valid);
        if (rb == 0 && (tid & 63) == 0) keepw[(size_t)b * 16 + (tid >> 6) + 4 * k] = bal;
    }

    red[tid] = lmax;
    __syncthreads();
    for (int s2 = 128; s2 > 0; s2 >>= 1) {
        if (tid < s2) red[tid] = fmax(red[tid], red[tid + s2]);
        __syncthreads();
    }
    double offscale = red[0] + 1.0;
    __syncthreads();

#pragma unroll
    for (int k = 0; k < 4; ++k) {
        int j = tid + k * 256;
        double o = (double)cls_[k] * offscale;
        double ox1 = vx1[k] + o, oy1 = vy1[k] + o;
        double ox2 = vx2[k] + o, oy2 = vy2[k] + o;
        lx1[j] = ox1; ly1[j] = oy1; lx2[j] = ox2; ly2[j] = oy2;
        lar[j] = (ox2 - ox1 + 1.0) * (oy2 - oy1 + 1.0);
        if (rb == 0 && j < KTOP) {
            size_t ix = (size_t)b * 1024 + j;
            outs[ix] = (float)sc[k];
            outc[ix] = (float)cls_[k];
            ((float4*)outb)[ix] = make_float4((float)vx1[k], (float)vy1[k],
                                              (float)vx2[k], (float)vy2[k]);
        }
    }
    __syncthreads();

    int rl = tid >> 2;          // 0..63
    int wq = tid & 3;
    int r = rb * 64 + rl;
    double rx1 = lx1[r], ry1 = ly1[r], rx2 = lx2[r], ry2 = ly2[r], ra = lar[r];

    uint64_t orw = 0;           // OR of this thread's 4 words of row r
#pragma unroll
    for (int ww = 0; ww < 4; ++ww) {
        int w = ww * 4 + wq;
        uint64_t bits = 0;
        if (w * 64 + 63 > r) {
            for (int kk = 0; kk < 64; ++kk) {
                int j = w * 64 + kk;
                double xmn = fmax(lx1[j], rx1);
                double ymn = fmax(ly1[j], ry1);
                double xmx = fmin(lx2[j], rx2);
                double ymx = fmin(ly2[j], ry2);
                double iw = xmx - xmn; iw = iw < 0.0 ? 0.0 : iw;
                double ih = ymx - ymn; ih = ih < 0.0 ? 0.0 : ih;
                double inter = iw * ih;
                double iou = inter / (ra + lar[j] - inter);   // f64 div: bit-exact vs ref
                bits |= ((uint64_t)((j > r) && (iou > D_IOU_THR))) << kk;
            }
        }
        orw |= bits;
        M[((size_t)b * 1024 + r) * 16 + w] = bits;
        if (w == rb) D[((size_t)b * 16 + rb) * 64 + rl] = bits;
    }

    // row-nonzero flag: OR across the 4 lanes handling row r (lanes 4k..4k+3)
    uint32_t o32 = (uint32_t)(orw | (orw >> 32));
    o32 |= __shfl_xor((int)o32, 1, 64);
    o32 |= __shfl_xor((int)o32, 2, 64);
    if (wq == 0) Rnz[(size_t)b * 1024 + r] = (o32 != 0) ? 1u : 0u;
}

// ---------------- S3: one-wave sparse scan ----------------
// Common case (random data): almost no row suppresses anything -> nz masks are
// ~empty -> every group is a uniform skip. Worst case degenerates to the dense
// resolve (still correct).

#define LOADC(G)                                                               \
    C0  = Mb[((size_t)(G) * 64 +  0 + p) * 16 + w];                            \
    C1  = Mb[((size_t)(G) * 64 +  4 + p) * 16 + w];                            \
    C2  = Mb[((size_t)(G) * 64 +  8 + p) * 16 + w];                            \
    C3  = Mb[((size_t)(G) * 64 + 12 + p) * 16 + w];                            \
    C4  = Mb[((size_t)(G) * 64 + 16 + p) * 16 + w];                            \
    C5  = Mb[((size_t)(G) * 64 + 20 + p) * 16 + w];                            \
    C6  = Mb[((size_t)(G) * 64 + 24 + p) * 16 + w];                            \
    C7  = Mb[((size_t)(G) * 64 + 28 + p) * 16 + w];                            \
    C8  = Mb[((size_t)(G) * 64 + 32 + p) * 16 + w];                            \
    C9  = Mb[((size_t)(G) * 64 + 36 + p) * 16 + w];                            \
    C10 = Mb[((size_t)(G) * 64 + 40 + p) * 16 + w];                            \
    C11 = Mb[((size_t)(G) * 64 + 44 + p) * 16 + w];                            \
    C12 = Mb[((size_t)(G) * 64 + 48 + p) * 16 + w];                            \
    C13 = Mb[((size_t)(G) * 64 + 52 + p) * 16 + w];                            \
    C14 = Mb[((size_t)(G) * 64 + 56 + p) * 16 + w];                            \
    C15 = Mb[((size_t)(G) * 64 + 60 + p) * 16 + w];

#define APPLY_Q(q)                                                             \
    {                                                                          \
        uint64_t t_ = (alive >> (4 * (q) + p)) & 1ull;                         \
        acc &= ~(C##q & (0ull - t_));                                          \
    }

#define STEPG(G)                                                               \
    {                                                                          \
        uint64_t kg = rl64(kw, (G));                                           \
        if (kg & nz##G) {                                                      \
            uint64_t dg = Dp[(size_t)(G) * 64 + lane];                         \
            LOADC(G)                                                           \
            uint64_t cur = kg, it = kg & nz##G;                                \
            while (it) {                                                       \
                int kk = __builtin_ctzll(it);                                  \
                uint64_t dk = rl64(dg, kk);                                    \
                cur &= ~dk;                                                    \
                it &= ~dk;                                                     \
                it &= it - 1ull;                                               \
            }                                                                  \
            uint64_t alive = cur;                                              \
            uint64_t acc = ~0ull;                                              \
            APPLY_Q(0)  APPLY_Q(1)  APPLY_Q(2)  APPLY_Q(3)                     \
            APPLY_Q(4)  APPLY_Q(5)  APPLY_Q(6)  APPLY_Q(7)                     \
            APPLY_Q(8)  APPLY_Q(9)  APPLY_Q(10) APPLY_Q(11)                    \
            APPLY_Q(12) APPLY_Q(13) APPLY_Q(14) APPLY_Q(15)                    \
            acc &= __shfl_xor(acc, 16, 64);                                    \
            acc &= __shfl_xor(acc, 32, 64);                                    \
            kw &= acc;                                                         \
        }                                                                      \
    }

__global__ __launch_bounds__(64, 1) void k_scan(
    const uint64_t* __restrict__ M, const uint64_t* __restrict__ D,
    const uint32_t* __restrict__ Rnz, const uint64_t* __restrict__ keepw,
    const float* __restrict__ outs, const float* __restrict__ outc,
    const float* __restrict__ outb, float* __restrict__ out)
{
    int b = blockIdx.x;
    int lane = threadIdx.x;          // one wave
    int p = (lane >> 4) & 3;         // replica 0..3
    int w = lane & 15;               // word index
    const uint64_t* Mb = M + (size_t)b * 1024 * 16;
    const uint64_t* Dp = D + (size_t)b * 1024;
    const uint32_t* Rp = Rnz + (size_t)b * 1024;

    uint64_t kw = keepw[(size_t)b * 16 + w];   // word w, replicated x4

    // load all row flags up front (16 coalesced loads), then ballots
    uint32_t f0  = Rp[0 * 64 + lane],  f1  = Rp[1 * 64 + lane];
    uint32_t f2  = Rp[2 * 64 + lane],  f3  = Rp[3 * 64 + lane];
    uint32_t f4  = Rp[4 * 64 + lane],  f5  = Rp[5 * 64 + lane];
    uint32_t f6  = Rp[6 * 64 + lane],  f7  = Rp[7 * 64 + lane];
    uint32_t f8  = Rp[8 * 64 + lane],  f9  = Rp[9 * 64 + lane];
    uint32_t f10 = Rp[10 * 64 + lane], f11 = Rp[11 * 64 + lane];
    uint32_t f12 = Rp[12 * 64 + lane], f13 = Rp[13 * 64 + lane];
    uint32_t f14 = Rp[14 * 64 + lane], f15 = Rp[15 * 64 + lane];
    uint64_t nz0  = __ballot(f0 != 0),  nz1  = __ballot(f1 != 0);
    uint64_t nz2  = __ballot(f2 != 0),  nz3  = __ballot(f3 != 0);
    uint64_t nz4  = __ballot(f4 != 0),  nz5  = __ballot(f5 != 0);
    uint64_t nz6  = __ballot(f6 != 0),  nz7  = __ballot(f7 != 0);
    uint64_t nz8  = __ballot(f8 != 0),  nz9  = __ballot(f9 != 0);
    uint64_t nz10 = __ballot(f10 != 0), nz11 = __ballot(f11 != 0);
    uint64_t nz12 = __ballot(f12 != 0), nz13 = __ballot(f13 != 0);
    uint64_t nz14 = __ballot(f14 != 0), nz15 = __ballot(f15 != 0);

    uint64_t C0,C1,C2,C3,C4,C5,C6,C7,C8,C9,C10,C11,C12,C13,C14,C15;

    STEPG(0)  STEPG(1)  STEPG(2)  STEPG(3)
    STEPG(4)  STEPG(5)  STEPG(6)  STEPG(7)
    STEPG(8)  STEPG(9)  STEPG(10) STEPG(11)
    STEPG(12) STEPG(13) STEPG(14) STEPG(15)

    // outputs: keep word for row-block t is uniform (readlane), bit = lane
#pragma unroll
    for (int t = 0; t < 16; ++t) {
        int j = t * 64 + lane;
        uint64_t kwt = rl64(kw, t);
        bool kp = (kwt >> lane) & 1ull;
        if (j < KTOP) {
            size_t ix = (size_t)b * 1024 + j;
            out[(size_t)b * KTOP + j] = kp ? outs[ix] : 0.0f;
            out[(size_t)NB * KTOP + (size_t)b * KTOP + j] = kp ? outc[ix] : 0.0f;
            float4 bb = kp ? ((const float4*)outb)[ix] : make_float4(0.f, 0.f, 0.f, 0.f);
            ((float4*)(out + 2 * (size_t)NB * KTOP))[(size_t)b * KTOP + j] = bb;
        }
    }
}

// ---------------- launch ----------------

extern "C" void kernel_launch(void* const* d_in, const int* in_sizes, int n_in,
                              void* d_out, int out_size, void* d_ws, size_t ws_size,
                              hipStream_t stream) {
    const float* cls[5];
    const float* cnt[5];
    const float* reg[5];
    for (int i = 0; i < 5; ++i) {
        cls[i] = (const float*)d_in[i];
        cnt[i] = (const float*)d_in[5 + i];
        reg[i] = (const float*)d_in[10 + i];
    }
    float* out = (float*)d_out;

    // ws layout (bytes); M reuses the packed region (packed dead after k_select)
    char* ws = (char*)d_ws;
    uint64_t* packed  = (uint64_t*)(ws + 0);          // 8*16384*8     = 1,048,576
    uint64_t* M       = (uint64_t*)(ws + 0);          // 8*1024*16*8   = 1,048,576 (reuse)
    int*      classes = (int*)     (ws + 1048576);    // 8*13343*4     =   426,976
    uint64_t* tkeys   = (uint64_t*)(ws + 1475552);    // 8*1024*8      =    65,536
    uint64_t* D       = (uint64_t*)(ws + 1541088);    // 8*16*64*8     =    65,536
    uint64_t* keepw   = (uint64_t*)(ws + 1606624);    // 8*16*8        =     1,024
    float*    outs    = (float*)   (ws + 1607648);    // 8*1024*4      =    32,768
    float*    outc    = (float*)   (ws + 1640416);    // 8*1024*4      =    32,768
    float*    outb    = (float*)   (ws + 1673184);    // 8*1024*16     =   131,072
    uint32_t* Rnz     = (uint32_t*)(ws + 1804256);    // 8*1024*4      =    32,768

    k_scores<<<(NB * PPAD) / 256, 256, 0, stream>>>(
        cls[0], cls[1], cls[2], cls[3], cls[4],
        cnt[0], cnt[1], cnt[2], cnt[3], cnt[4],
        packed, classes);

    k_select<<<NB, 512, 0, stream>>>(packed, tkeys);

    k_boxmask<<<NB * 16, 256, 0, stream>>>(tkeys, classes,
                                           reg[0], reg[1], reg[2], reg[3], reg[4],
                                           outs, outc, outb, keepw, M, D, Rnz);

    k_scan<<<NB, 64, 0, stream>>>(M, D, Rnz, keepw, outs, outc, outb, out);
}

// Round 7
// 102.052 us; speedup vs baseline: 1.6826x; 1.0147x over previous
//
#include <hip/hip_runtime.h>
#include <math.h>
#include <stdint.h>

#define NB 8
#define P_TOTAL 13343
#define NCLS 80
#define KTOP 1000
#define PPAD 16384
#define D_SCORE_THR 0.05
#define D_IOU_THR 0.6

// ---------------- helpers ----------------

__device__ __forceinline__ double sig64(double x) {
    if (x >= 0.0) {
        double e = exp(-x);
        return 1.0 / (1.0 + e);
    } else {
        double e = exp(x);
        return e / (1.0 + e);
    }
}

// key = score bits (top 50) | (0x3FFF - idx): descending sort => score desc, idx asc
__device__ __forceinline__ uint64_t pack_key(double s, int p) {
    uint64_t b = (uint64_t)__double_as_longlong(s);
    return (b & ~0x3FFFull) | (uint64_t)(0x3FFF - p);
}

__device__ __forceinline__ uint64_t rl64(uint64_t v, int l) {
    uint32_t lo = (uint32_t)__builtin_amdgcn_readlane((int)(uint32_t)v, l);
    uint32_t hi = (uint32_t)__builtin_amdgcn_readlane((int)(uint32_t)(v >> 32), l);
    return ((uint64_t)hi << 32) | lo;
}

// Bitonic sort (descending) on uint64 keys in LDS. n power of two.
__device__ void bitonic_u64(uint64_t* sk, int n, int tid, int nthr) {
    for (int k2 = 2; k2 <= n; k2 <<= 1) {
        for (int j = k2 >> 1; j > 0; j >>= 1) {
            for (int t = tid; t < (n >> 1); t += nthr) {
                int i = ((t & ~(j - 1)) << 1) | (t & (j - 1));
                int l = i | j;
                uint64_t a = sk[i], b = sk[l];
                bool prec = (a > b);
                bool desc = ((i & k2) == 0);
                if (prec != desc) { sk[i] = b; sk[l] = a; }
            }
            __syncthreads();
        }
    }
}

// ---------------- S0: scores/classes -> packed keys ----------------

__global__ __launch_bounds__(256) void k_scores(
    const float* __restrict__ c0, const float* __restrict__ c1, const float* __restrict__ c2,
    const float* __restrict__ c3, const float* __restrict__ c4,
    const float* __restrict__ n0, const float* __restrict__ n1, const float* __restrict__ n2,
    const float* __restrict__ n3, const float* __restrict__ n4,
    uint64_t* __restrict__ packed, int* __restrict__ classes)
{
    int gid = blockIdx.x * 256 + threadIdx.x;
    if (gid >= NB * PPAD) return;
    int b = gid >> 14;
    int p = gid & (PPAD - 1);
    if (p >= P_TOTAL) { packed[gid] = 0; return; }

    int base, hw;
    const float* cls;
    const float* cnt;
    if (p < 10000)      { base = 0;     hw = 10000; cls = c0; cnt = n0; }
    else if (p < 12500) { base = 10000; hw = 2500;  cls = c1; cnt = n1; }
    else if (p < 13125) { base = 12500; hw = 625;   cls = c2; cnt = n2; }
    else if (p < 13294) { base = 13125; hw = 169;   cls = c3; cnt = n3; }
    else                { base = 13294; hw = 49;    cls = c4; cnt = n4; }
    int yx = p - base;

    const float* cp = cls + (size_t)b * NCLS * hw + yx;
    float m = -3.4e38f;
    int am = 0;
    for (int c = 0; c < NCLS; ++c) {
        float v = cp[(size_t)c * hw];
        if (v > m) { m = v; am = c; }   // first max, matches jnp.argmax
    }
    float cv = cnt[(size_t)b * hw + yx];
    double s = sqrt(sig64((double)m) * sig64((double)cv));

    packed[gid] = pack_key(s, p);
    classes[(size_t)b * P_TOTAL + p] = am + 1;
}

// ---------------- S1: value-histogram select + sort -> top 1024 ----------------

__global__ __launch_bounds__(512) void k_select(
    const uint64_t* __restrict__ packed, uint64_t* __restrict__ tkeys)
{
    __shared__ uint32_t hist[2048];
    __shared__ uint64_t cand[2048];
    __shared__ uint32_t chs[64];
    __shared__ int sB, sC1, sB2, sCnt;
    int b = blockIdx.x;
    int tid = threadIdx.x;
    const uint64_t* pk = packed + (size_t)b * PPAD;

    for (int t = tid; t < 2048; t += 512) hist[t] = 0;
    __syncthreads();

    // pass 1: coarse 2048-bin VALUE histogram (well-spread for s in [0,1])
    for (int t = tid; t < PPAD; t += 512) {
        double s = __longlong_as_double((long long)(pk[t] & ~0x3FFFull));
        int bin = (int)(s * 2048.0);
        bin = bin < 0 ? 0 : (bin > 2047 ? 2047 : bin);
        atomicAdd(&hist[bin], 1u);
    }
    __syncthreads();
    if (tid < 64) {
        uint32_t ssum = 0;
        for (int i = 0; i < 32; ++i) ssum += hist[tid * 32 + i];
        chs[tid] = ssum;
    }
    __syncthreads();
    if (tid == 0) {
        int acc = 0, c = 63;
        for (; c > 0; --c) { if (acc + (int)chs[c] >= 1024) break; acc += (int)chs[c]; }
        int bfound = c * 32;
        for (int bb = c * 32 + 31; bb >= c * 32; --bb) {
            if (acc + (int)hist[bb] >= 1024) { bfound = bb; break; }
            acc += (int)hist[bb];
        }
        sB = bfound; sC1 = acc;   // acc = count of keys with bin > sB
    }
    __syncthreads();
    int B = sB;
    for (int t = tid; t < 2048; t += 512) hist[t] = 0;
    __syncthreads();

    // pass 2: refine crossing bin into 2048 sub-bins
    for (int t = tid; t < PPAD; t += 512) {
        double s = __longlong_as_double((long long)(pk[t] & ~0x3FFFull));
        int bin = (int)(s * 2048.0);
        bin = bin < 0 ? 0 : (bin > 2047 ? 2047 : bin);
        if (bin == B) {
            int sub = (int)(s * 4194304.0) - B * 2048;
            sub = sub < 0 ? 0 : (sub > 2047 ? 2047 : sub);
            atomicAdd(&hist[sub], 1u);
        }
    }
    __syncthreads();
    if (tid < 64) {
        uint32_t ssum = 0;
        for (int i = 0; i < 32; ++i) ssum += hist[tid * 32 + i];
        chs[tid] = ssum;
    }
    __syncthreads();
    if (tid == 0) {
        int acc = sC1, c = 63;
        for (; c > 0; --c) { if (acc + (int)chs[c] >= 1024) break; acc += (int)chs[c]; }
        int bfound = c * 32;
        for (int bb = c * 32 + 31; bb >= c * 32; --bb) {
            if (acc + (int)hist[bb] >= 1024) { bfound = bb; break; }
            acc += (int)hist[bb];
        }
        sB2 = bfound;
        sCnt = 0;
    }
    __syncthreads();
    int B2 = sB2;

    // pass 3: compact candidates (exact-rank superset; sort canonicalizes)
    for (int t = tid; t < PPAD; t += 512) {
        uint64_t key = pk[t];
        double s = __longlong_as_double((long long)(key & ~0x3FFFull));
        int bin = (int)(s * 2048.0);
        bin = bin < 0 ? 0 : (bin > 2047 ? 2047 : bin);
        bool pred = false;
        if (bin > B) pred = true;
        else if (bin == B) {
            int sub = (int)(s * 4194304.0) - B * 2048;
            sub = sub < 0 ? 0 : (sub > 2047 ? 2047 : sub);
            pred = (sub >= B2);
        }
        if (pred) {
            int slot = atomicAdd(&sCnt, 1);
            if (slot < 2048) cand[slot] = key;
        }
    }
    __syncthreads();
    int cnt = sCnt < 2048 ? sCnt : 2048;

    if (cnt <= 1024) {
        for (int t = tid; t < 1024; t += 512) if (t >= cnt) cand[t] = 0;
        __syncthreads();
        bitonic_u64(cand, 1024, tid, 512);
    } else {
        for (int t = tid; t < 2048; t += 512) if (t >= cnt) cand[t] = 0;
        __syncthreads();
        bitonic_u64(cand, 2048, tid, 512);
    }

    for (int t = tid; t < 1024; t += 512)
        tkeys[(size_t)b * 1024 + t] = cand[t];
}

// ---------------- S2: box gather + offsets + prefiltered mask matrix ------------

__global__ __launch_bounds__(256) void k_boxmask(
    const uint64_t* __restrict__ tkeys, const int* __restrict__ classes,
    const float* __restrict__ r0, const float* __restrict__ r1, const float* __restrict__ r2,
    const float* __restrict__ r3, const float* __restrict__ r4,
    float* __restrict__ outs, float* __restrict__ outc, float* __restrict__ outb,
    uint64_t* __restrict__ keepw,
    uint64_t* __restrict__ M, uint64_t* __restrict__ D,
    uint32_t* __restrict__ Rnz)
{
    __shared__ double lx1[1024], ly1[1024], lx2[1024], ly2[1024], lar[1024];
    __shared__ float fx1[1024], fy1[1024], fx2[1024], fy2[1024];
    __shared__ double red[256];
    __shared__ uint64_t ornz[4][64];
    int bid = blockIdx.x;
    int b = bid >> 4, rb = bid & 15;
    int tid = threadIdx.x;

    double vx1[4], vy1[4], vx2[4], vy2[4], sc[4];
    int cls_[4];
    double lmax = -1e300;

#pragma unroll
    for (int k = 0; k < 4; ++k) {
        int j = tid + k * 256;
        uint64_t key = tkeys[(size_t)b * 1024 + j];
        int idx = 0x3FFF - (int)(key & 0x3FFF);
        idx = idx < 0 ? 0 : (idx > P_TOTAL - 1 ? P_TOTAL - 1 : idx);
        double s = __longlong_as_double((long long)(key & ~0x3FFFull));

        int base, w, hw, st;
        const float* reg;
        if (idx < 10000)      { base = 0;     w = 100; hw = 10000; st = 8;   reg = r0; }
        else if (idx < 12500) { base = 10000; w = 50;  hw = 2500;  st = 16;  reg = r1; }
        else if (idx < 13125) { base = 12500; w = 25;  hw = 625;   st = 32;  reg = r2; }
        else if (idx < 13294) { base = 13125; w = 13;  hw = 169;   st = 64;  reg = r3; }
        else                  { base = 13294; w = 7;   hw = 49;    st = 128; reg = r4; }
        int yx = idx - base;
        int y = yx / w;
        int x = yx - y * w;
        double sx = (double)(x * st + st / 2);
        double sy = (double)(y * st + st / 2);
        const float* rp = reg + (size_t)b * 4 * hw + yx;
        double x1 = sx - (double)rp[0];
        double y1 = sy - (double)rp[hw];
        double x2 = sx + (double)rp[2 * (size_t)hw];
        double y2 = sy + (double)rp[3 * (size_t)hw];
        int cv = classes[(size_t)b * P_TOTAL + idx];

        bool valid = (j < KTOP) && (s >= D_SCORE_THR);
        if (j < KTOP) {
            lmax = fmax(lmax, valid ? x1 : 0.0);
            lmax = fmax(lmax, valid ? y1 : 0.0);
            lmax = fmax(lmax, valid ? x2 : 0.0);
            lmax = fmax(lmax, valid ? y2 : 0.0);
        }
        vx1[k] = x1; vy1[k] = y1; vx2[k] = x2; vy2[k] = y2;
        sc[k] = s; cls_[k] = cv;

        uint64_t bal = __ballot(valid);
        if (rb == 0 && (tid & 63) == 0) keepw[(size_t)b * 16 + (tid >> 6) + 4 * k] = bal;
    }

    red[tid] = lmax;
    __syncthreads();
    for (int s2 = 128; s2 > 0; s2 >>= 1) {
        if (tid < s2) red[tid] = fmax(red[tid], red[tid + s2]);
        __syncthreads();
    }
    double offscale = red[0] + 1.0;
    __syncthreads();

#pragma unroll
    for (int k = 0; k < 4; ++k) {
        int j = tid + k * 256;
        double o = (double)cls_[k] * offscale;
        double ox1 = vx1[k] + o, oy1 = vy1[k] + o;
        double ox2 = vx2[k] + o, oy2 = vy2[k] + o;
        lx1[j] = ox1; ly1[j] = oy1; lx2[j] = ox2; ly2[j] = oy2;
        lar[j] = (ox2 - ox1 + 1.0) * (oy2 - oy1 + 1.0);
        fx1[j] = (float)ox1; fy1[j] = (float)oy1;
        fx2[j] = (float)ox2; fy2[j] = (float)oy2;
        if (rb == 0 && j < KTOP) {
            size_t ix = (size_t)b * 1024 + j;
            outs[ix] = (float)sc[k];
            outc[ix] = (float)cls_[k];
            ((float4*)outb)[ix] = make_float4((float)vx1[k], (float)vy1[k],
                                              (float)vx2[k], (float)vy2[k]);
        }
    }
    __syncthreads();

    // phase B: lane = row, wave = 4-word column slice. All inner-loop LDS reads
    // are wave-uniform (broadcast, conflict-free). f32 conservative prefilter
    // (margin -0.5 >> max conversion error ~0.05); exact f64 IoU only for the
    // rare passers -- bit-identical decision math.
    int ww = tid >> 6;          // wave 0..3 -> words ww*4..ww*4+3
    int l  = tid & 63;          // lane = local row
    int r  = rb * 64 + l;       // global row
    float frx1 = fx1[r], fry1 = fy1[r], frx2 = fx2[r], fry2 = fy2[r];
    double rx1 = lx1[r], ry1 = ly1[r], rx2 = lx2[r], ry2 = ly2[r], ra = lar[r];
    int wbase = ww * 4;

    uint64_t bits0 = 0, bits1 = 0, bits2 = 0, bits3 = 0;

#define COLWORD(Q, BITS)                                                       \
    {                                                                          \
        int cb = (wbase + (Q)) * 64;                                           \
        if (cb + 63 > r) {                                                     \
            for (int kk = 0; kk < 64; ++kk) {                                  \
                int j = cb + kk;                                               \
                float xm = fminf(fx2[j], frx2) - fmaxf(fx1[j], frx1);          \
                float ym = fminf(fy2[j], fry2) - fmaxf(fy1[j], fry1);          \
                if (xm > -0.5f && ym > -0.5f) {                                \
                    double xmn = fmax(lx1[j], rx1);                            \
                    double ymn = fmax(ly1[j], ry1);                            \
                    double xmx = fmin(lx2[j], rx2);                            \
                    double ymx = fmin(ly2[j], ry2);                            \
                    double iw = xmx - xmn; iw = iw < 0.0 ? 0.0 : iw;           \
                    double ih = ymx - ymn; ih = ih < 0.0 ? 0.0 : ih;           \
                    double inter = iw * ih;                                    \
                    double iou = inter / (ra + lar[j] - inter);                \
                    BITS |= ((uint64_t)((j > r) && (iou > D_IOU_THR))) << kk;  \
                }                                                              \
            }                                                                  \
        }                                                                      \
    }

    COLWORD(0, bits0) COLWORD(1, bits1) COLWORD(2, bits2) COLWORD(3, bits3)
#undef COLWORD

    size_t mrow = ((size_t)b * 1024 + r) * 16 + wbase;
    M[mrow + 0] = bits0; M[mrow + 1] = bits1;
    M[mrow + 2] = bits2; M[mrow + 3] = bits3;

    // diagonal word (w == rb) -> D, written by the owning wave
    if (ww == (rb >> 2)) {
        uint64_t db = (rb & 3) == 0 ? bits0 : (rb & 3) == 1 ? bits1
                    : (rb & 3) == 2 ? bits2 : bits3;
        D[((size_t)b * 16 + rb) * 64 + l] = db;
    }

    // row-nonzero flag: OR across the 4 waves' word groups
    ornz[ww][l] = bits0 | bits1 | bits2 | bits3;
    __syncthreads();
    if (ww == 0) {
        uint64_t o = ornz[0][l] | ornz[1][l] | ornz[2][l] | ornz[3][l];
        Rnz[(size_t)b * 1024 + r] = (o != 0) ? 1u : 0u;
    }
}

// ---------------- S3: one-wave sparse scan ----------------

#define LOADC(G)                                                               \
    C0  = Mb[((size_t)(G) * 64 +  0 + p) * 16 + w];                            \
    C1  = Mb[((size_t)(G) * 64 +  4 + p) * 16 + w];                            \
    C2  = Mb[((size_t)(G) * 64 +  8 + p) * 16 + w];                            \
    C3  = Mb[((size_t)(G) * 64 + 12 + p) * 16 + w];                            \
    C4  = Mb[((size_t)(G) * 64 + 16 + p) * 16 + w];                            \
    C5  = Mb[((size_t)(G) * 64 + 20 + p) * 16 + w];                            \
    C6  = Mb[((size_t)(G) * 64 + 24 + p) * 16 + w];                            \
    C7  = Mb[((size_t)(G) * 64 + 28 + p) * 16 + w];                            \
    C8  = Mb[((size_t)(G) * 64 + 32 + p) * 16 + w];                            \
    C9  = Mb[((size_t)(G) * 64 + 36 + p) * 16 + w];                            \
    C10 = Mb[((size_t)(G) * 64 + 40 + p) * 16 + w];                            \
    C11 = Mb[((size_t)(G) * 64 + 44 + p) * 16 + w];                            \
    C12 = Mb[((size_t)(G) * 64 + 48 + p) * 16 + w];                            \
    C13 = Mb[((size_t)(G) * 64 + 52 + p) * 16 + w];                            \
    C14 = Mb[((size_t)(G) * 64 + 56 + p) * 16 + w];                            \
    C15 = Mb[((size_t)(G) * 64 + 60 + p) * 16 + w];

#define APPLY_Q(q)                                                             \
    {                                                                          \
        uint64_t t_ = (alive >> (4 * (q) + p)) & 1ull;                         \
        acc &= ~(C##q & (0ull - t_));                                          \
    }

#define STEPG(G)                                                               \
    {                                                                          \
        uint64_t kg = rl64(kw, (G));                                           \
        if (kg & nz##G) {                                                      \
            uint64_t dg = Dp[(size_t)(G) * 64 + lane];                         \
            LOADC(G)                                                           \
            uint64_t cur = kg, it = kg & nz##G;                                \
            while (it) {                                                       \
                int kk = __builtin_ctzll(it);                                  \
                uint64_t dk = rl64(dg, kk);                                    \
                cur &= ~dk;                                                    \
                it &= ~dk;                                                     \
                it &= it - 1ull;                                               \
            }                                                                  \
            uint64_t alive = cur;                                              \
            uint64_t acc = ~0ull;                                              \
            APPLY_Q(0)  APPLY_Q(1)  APPLY_Q(2)  APPLY_Q(3)                     \
            APPLY_Q(4)  APPLY_Q(5)  APPLY_Q(6)  APPLY_Q(7)                     \
            APPLY_Q(8)  APPLY_Q(9)  APPLY_Q(10) APPLY_Q(11)                    \
            APPLY_Q(12) APPLY_Q(13) APPLY_Q(14) APPLY_Q(15)                    \
            acc &= __shfl_xor(acc, 16, 64);                                    \
            acc &= __shfl_xor(acc, 32, 64);                                    \
            kw &= acc;                                                         \
        }                                                                      \
    }

__global__ __launch_bounds__(64, 1) void k_scan(
    const uint64_t* __restrict__ M, const uint64_t* __restrict__ D,
    const uint32_t* __restrict__ Rnz, const uint64_t* __restrict__ keepw,
    const float* __restrict__ outs, const float* __restrict__ outc,
    const float* __restrict__ outb, float* __restrict__ out)
{
    int b = blockIdx.x;
    int lane = threadIdx.x;          // one wave
    int p = (lane >> 4) & 3;         // replica 0..3
    int w = lane & 15;               // word index
    const uint64_t* Mb = M + (size_t)b * 1024 * 16;
    const uint64_t* Dp = D + (size_t)b * 1024;
    const uint32_t* Rp = Rnz + (size_t)b * 1024;

    uint64_t kw = keepw[(size_t)b * 16 + w];   // word w, replicated x4

    // load all row flags up front (16 coalesced loads), then ballots
    uint32_t f0  = Rp[0 * 64 + lane],  f1  = Rp[1 * 64 + lane];
    uint32_t f2  = Rp[2 * 64 + lane],  f3  = Rp[3 * 64 + lane];
    uint32_t f4  = Rp[4 * 64 + lane],  f5  = Rp[5 * 64 + lane];
    uint32_t f6  = Rp[6 * 64 + lane],  f7  = Rp[7 * 64 + lane];
    uint32_t f8  = Rp[8 * 64 + lane],  f9  = Rp[9 * 64 + lane];
    uint32_t f10 = Rp[10 * 64 + lane], f11 = Rp[11 * 64 + lane];
    uint32_t f12 = Rp[12 * 64 + lane], f13 = Rp[13 * 64 + lane];
    uint32_t f14 = Rp[14 * 64 + lane], f15 = Rp[15 * 64 + lane];
    uint64_t nz0  = __ballot(f0 != 0),  nz1  = __ballot(f1 != 0);
    uint64_t nz2  = __ballot(f2 != 0),  nz3  = __ballot(f3 != 0);
    uint64_t nz4  = __ballot(f4 != 0),  nz5  = __ballot(f5 != 0);
    uint64_t nz6  = __ballot(f6 != 0),  nz7  = __ballot(f7 != 0);
    uint64_t nz8  = __ballot(f8 != 0),  nz9  = __ballot(f9 != 0);
    uint64_t nz10 = __ballot(f10 != 0), nz11 = __ballot(f11 != 0);
    uint64_t nz12 = __ballot(f12 != 0), nz13 = __ballot(f13 != 0);
    uint64_t nz14 = __ballot(f14 != 0), nz15 = __ballot(f15 != 0);

    uint64_t C0,C1,C2,C3,C4,C5,C6,C7,C8,C9,C10,C11,C12,C13,C14,C15;

    STEPG(0)  STEPG(1)  STEPG(2)  STEPG(3)
    STEPG(4)  STEPG(5)  STEPG(6)  STEPG(7)
    STEPG(8)  STEPG(9)  STEPG(10) STEPG(11)
    STEPG(12) STEPG(13) STEPG(14) STEPG(15)

    // outputs: keep word for row-block t is uniform (readlane), bit = lane
#pragma unroll
    for (int t = 0; t < 16; ++t) {
        int j = t * 64 + lane;
        uint64_t kwt = rl64(kw, t);
        bool kp = (kwt >> lane) & 1ull;
        if (j < KTOP) {
            size_t ix = (size_t)b * 1024 + j;
            out[(size_t)b * KTOP + j] = kp ? outs[ix] : 0.0f;
            out[(size_t)NB * KTOP + (size_t)b * KTOP + j] = kp ? outc[ix] : 0.0f;
            float4 bb = kp ? ((const float4*)outb)[ix] : make_float4(0.f, 0.f, 0.f, 0.f);
            ((float4*)(out + 2 * (size_t)NB * KTOP))[(size_t)b * KTOP + j] = bb;
        }
    }
}

// ---------------- launch ----------------

extern "C" void kernel_launch(void* const* d_in, const int* in_sizes, int n_in,
                              void* d_out, int out_size, void* d_ws, size_t ws_size,
                              hipStream_t stream) {
    const float* cls[5];
    const float* cnt[5];
    const float* reg[5];
    for (int i = 0; i < 5; ++i) {
        cls[i] = (const float*)d_in[i];
        cnt[i] = (const float*)d_in[5 + i];
        reg[i] = (const float*)d_in[10 + i];
    }
    float* out = (float*)d_out;

    // ws layout (bytes); M reuses the packed region (packed dead after k_select)
    char* ws = (char*)d_ws;
    uint64_t* packed  = (uint64_t*)(ws + 0);          // 8*16384*8     = 1,048,576
    uint64_t* M       = (uint64_t*)(ws + 0);          // 8*1024*16*8   = 1,048,576 (reuse)
    int*      classes = (int*)     (ws + 1048576);    // 8*13343*4     =   426,976
    uint64_t* tkeys   = (uint64_t*)(ws + 1475552);    // 8*1024*8      =    65,536
    uint64_t* D       = (uint64_t*)(ws + 1541088);    // 8*16*64*8     =    65,536
    uint64_t* keepw   = (uint64_t*)(ws + 1606624);    // 8*16*8        =     1,024
    float*    outs    = (float*)   (ws + 1607648);    // 8*1024*4      =    32,768
    float*    outc    = (float*)   (ws + 1640416);    // 8*1024*4      =    32,768
    float*    outb    = (float*)   (ws + 1673184);    // 8*1024*16     =   131,072
    uint32_t* Rnz     = (uint32_t*)(ws + 1804256);    // 8*1024*4      =    32,768

    k_scores<<<(NB * PPAD) / 256, 256, 0, stream>>>(
        cls[0], cls[1], cls[2], cls[3], cls[4],
        cnt[0], cnt[1], cnt[2], cnt[3], cnt[4],
        packed, classes);

    k_select<<<NB, 512, 0, stream>>>(packed, tkeys);

    k_boxmask<<<NB * 16, 256, 0, stream>>>(tkeys, classes,
                                           reg[0], reg[1], reg[2], reg[3], reg[4],
                                           outs, outc, outb, keepw, M, D, Rnz);

    k_scan<<<NB, 64, 0, stream>>>(M, D, Rnz, keepw, outs, outc, outb, out);
}

// Round 8
// 88.475 us; speedup vs baseline: 1.9409x; 1.1535x over previous
//
#include <hip/hip_runtime.h>
#include <math.h>
#include <stdint.h>

#define NB 8
#define P_TOTAL 13343
#define NCLS 80
#define KTOP 1000
#define PPAD 16384
#define D_SCORE_THR 0.05
#define D_IOU_THR 0.6

// ---------------- helpers ----------------

__device__ __forceinline__ double sig64(double x) {
    if (x >= 0.0) {
        double e = exp(-x);
        return 1.0 / (1.0 + e);
    } else {
        double e = exp(x);
        return e / (1.0 + e);
    }
}

// key = score bits (top 50) | (0x3FFF - idx): descending sort => score desc, idx asc
__device__ __forceinline__ uint64_t pack_key(double s, int p) {
    uint64_t b = (uint64_t)__double_as_longlong(s);
    return (b & ~0x3FFFull) | (uint64_t)(0x3FFF - p);
}

__device__ __forceinline__ double key_score(uint64_t key) {
    return __longlong_as_double((long long)(key & ~0x3FFFull));
}

__device__ __forceinline__ int val_bin(double s) {
    int bin = (int)(s * 2048.0);
    return bin < 0 ? 0 : (bin > 2047 ? 2047 : bin);
}

__device__ __forceinline__ uint64_t rl64(uint64_t v, int l) {
    uint32_t lo = (uint32_t)__builtin_amdgcn_readlane((int)(uint32_t)v, l);
    uint32_t hi = (uint32_t)__builtin_amdgcn_readlane((int)(uint32_t)(v >> 32), l);
    return ((uint64_t)hi << 32) | lo;
}

// Bitonic sort (descending) on uint64 keys in LDS. n power of two.
__device__ void bitonic_u64(uint64_t* sk, int n, int tid, int nthr) {
    for (int k2 = 2; k2 <= n; k2 <<= 1) {
        for (int j = k2 >> 1; j > 0; j >>= 1) {
            for (int t = tid; t < (n >> 1); t += nthr) {
                int i = ((t & ~(j - 1)) << 1) | (t & (j - 1));
                int l = i | j;
                uint64_t a = sk[i], b = sk[l];
                bool prec = (a > b);
                bool desc = ((i & k2) == 0);
                if (prec != desc) { sk[i] = b; sk[l] = a; }
            }
            __syncthreads();
        }
    }
}

// ---------------- S0: scores/classes -> packed keys ----------------

__global__ __launch_bounds__(256) void k_scores(
    const float* __restrict__ c0, const float* __restrict__ c1, const float* __restrict__ c2,
    const float* __restrict__ c3, const float* __restrict__ c4,
    const float* __restrict__ n0, const float* __restrict__ n1, const float* __restrict__ n2,
    const float* __restrict__ n3, const float* __restrict__ n4,
    uint64_t* __restrict__ packed, int* __restrict__ classes)
{
    int gid = blockIdx.x * 256 + threadIdx.x;
    if (gid >= NB * PPAD) return;
    int b = gid >> 14;
    int p = gid & (PPAD - 1);
    if (p >= P_TOTAL) { packed[gid] = 0; return; }

    int base, hw;
    const float* cls;
    const float* cnt;
    if (p < 10000)      { base = 0;     hw = 10000; cls = c0; cnt = n0; }
    else if (p < 12500) { base = 10000; hw = 2500;  cls = c1; cnt = n1; }
    else if (p < 13125) { base = 12500; hw = 625;   cls = c2; cnt = n2; }
    else if (p < 13294) { base = 13125; hw = 169;   cls = c3; cnt = n3; }
    else                { base = 13294; hw = 49;    cls = c4; cnt = n4; }
    int yx = p - base;

    const float* cp = cls + (size_t)b * NCLS * hw + yx;
    float m = -3.4e38f;
    int am = 0;
    for (int c = 0; c < NCLS; ++c) {
        float v = cp[(size_t)c * hw];
        if (v > m) { m = v; am = c; }   // first max, matches jnp.argmax
    }
    float cv = cnt[(size_t)b * hw + yx];
    double s = sqrt(sig64((double)m) * sig64((double)cv));

    packed[gid] = pack_key(s, p);
    classes[(size_t)b * P_TOTAL + p] = am + 1;
}

// ---------------- S1: fused select (hist + parallel threshold + sort) + prep ----

__global__ __launch_bounds__(1024) void k_selprep(
    const uint64_t* __restrict__ packed, const int* __restrict__ classes,
    const float* __restrict__ r0, const float* __restrict__ r1, const float* __restrict__ r2,
    const float* __restrict__ r3, const float* __restrict__ r4,
    double4* __restrict__ rawbox, float* __restrict__ clsall,
    float* __restrict__ outs, float* __restrict__ outc, float* __restrict__ outb,
    uint64_t* __restrict__ keepw, double* __restrict__ pmax)
{
    __shared__ uint32_t hist[2048];
    __shared__ uint64_t cand[2048];
    __shared__ uint32_t chs[64];
    __shared__ double red16[16];
    __shared__ int sB, sCnt;
    int b = blockIdx.x;
    int tid = threadIdx.x;
    int lane = tid & 63, wid = tid >> 6;
    const uint64_t* pk = packed + (size_t)b * PPAD;

    for (int t = tid; t < 2048; t += 1024) hist[t] = 0;
    if (tid == 0) sCnt = 0;
    __syncthreads();

    // pass 1: 2048-bin value histogram
    for (int t = tid; t < PPAD; t += 1024)
        atomicAdd(&hist[val_bin(key_score(pk[t]))], 1u);
    __syncthreads();

    if (tid < 64) {
        uint32_t ss = 0;
        for (int i = 0; i < 32; ++i) ss += hist[tid * 32 + i];
        chs[tid] = ss;
    }
    __syncthreads();

    // parallel threshold: find largest bin B with count(bin >= B) >= 1024
    if (wid == 0) {
        // chunk-level: suffix sums via reversed prefix scan
        uint32_t v = chs[63 - lane];
        uint32_t P = v;
        for (int d = 1; d < 64; d <<= 1) {
            uint32_t u = __shfl_up(P, d, 64);
            if (lane >= d) P += u;
        }
        uint64_t bal = __ballot(P >= 1024u);
        int lstar = __builtin_ctzll(bal);           // exists: total = 16384
        int cstar = 63 - lstar;
        uint32_t Pst = (uint32_t)__shfl((int)P, lstar, 64);
        uint32_t C1c = Pst - chs[cstar];            // count in chunks > cstar
        // bin-level within chunk cstar
        uint32_t w = (lane < 32) ? hist[cstar * 32 + 31 - lane] : 0u;
        uint32_t Q = w;
        for (int d = 1; d < 32; d <<= 1) {
            uint32_t u = __shfl_up(Q, d, 64);
            if (lane >= d) Q += u;
        }
        uint64_t bal2 = __ballot((lane < 32) && (C1c + Q >= 1024u));
        int l2 = __builtin_ctzll(bal2);
        if (lane == 0) sB = cstar * 32 + 31 - l2;
    }
    __syncthreads();
    int B = sB;

    // compaction: bin >= B (superset of top-1024; sort canonicalizes).
    // wave-aggregated slot allocation: 1 LDS atomic per wave-iteration.
    for (int t = tid; t < PPAD; t += 1024) {
        uint64_t key = pk[t];
        bool pred = (val_bin(key_score(key)) >= B);
        uint64_t bal = __ballot(pred);
        int base = 0;
        if (lane == 0) base = atomicAdd(&sCnt, __popcll(bal));
        base = __shfl(base, 0, 64);
        if (pred) {
            int slot = base + __popcll(bal & ((1ull << lane) - 1ull));
            if (slot < 2048) cand[slot] = key;
        }
    }
    __syncthreads();
    int cnt = sCnt < 2048 ? sCnt : 2048;
    for (int t = tid; t < 2048; t += 1024) if (t >= cnt) cand[t] = 0;
    __syncthreads();

    bitonic_u64(cand, 2048, tid, 1024);   // ends with __syncthreads

    // gather phase: thread tid owns row j = tid (top-1024 in cand[0..1023])
    int j = tid;
    uint64_t key = cand[j];
    int idx = 0x3FFF - (int)(key & 0x3FFF);
    idx = idx < 0 ? 0 : (idx > P_TOTAL - 1 ? P_TOTAL - 1 : idx);
    double s = key_score(key);

    int base2, w2, hw, st;
    const float* reg;
    if (idx < 10000)      { base2 = 0;     w2 = 100; hw = 10000; st = 8;   reg = r0; }
    else if (idx < 12500) { base2 = 10000; w2 = 50;  hw = 2500;  st = 16;  reg = r1; }
    else if (idx < 13125) { base2 = 12500; w2 = 25;  hw = 625;   st = 32;  reg = r2; }
    else if (idx < 13294) { base2 = 13125; w2 = 13;  hw = 169;   st = 64;  reg = r3; }
    else                  { base2 = 13294; w2 = 7;   hw = 49;    st = 128; reg = r4; }
    int yx = idx - base2;
    int y = yx / w2;
    int x = yx - y * w2;
    double sx = (double)(x * st + st / 2);
    double sy = (double)(y * st + st / 2);
    const float* rp = reg + (size_t)b * 4 * hw + yx;
    double x1 = sx - (double)rp[0];
    double y1 = sy - (double)rp[hw];
    double x2 = sx + (double)rp[2 * (size_t)hw];
    double y2 = sy + (double)rp[3 * (size_t)hw];
    int cv = classes[(size_t)b * P_TOTAL + idx];

    bool valid = (j < KTOP) && (s >= D_SCORE_THR);
    double lmax = -1e300;
    if (j < KTOP) {
        lmax = fmax(lmax, valid ? x1 : 0.0);
        lmax = fmax(lmax, valid ? y1 : 0.0);
        lmax = fmax(lmax, valid ? x2 : 0.0);
        lmax = fmax(lmax, valid ? y2 : 0.0);
    }
    // wave fmax reduce (exactly associative) -> block reduce
    for (int d = 1; d < 64; d <<= 1)
        lmax = fmax(lmax, __shfl_xor(lmax, d, 64));
    if (lane == 0) red16[wid] = lmax;
    uint64_t balv = __ballot(valid);
    if (lane == 0) keepw[(size_t)b * 16 + wid] = balv;
    __syncthreads();
    if (tid == 0) {
        double m = red16[0];
        for (int i = 1; i < 16; ++i) m = fmax(m, red16[i]);
        pmax[b] = m;
    }

    size_t ix = (size_t)b * 1024 + j;
    rawbox[ix] = make_double4(x1, y1, x2, y2);
    clsall[ix] = (float)cv;
    if (j < KTOP) {
        outs[ix] = (float)s;
        outc[ix] = (float)cv;
        ((float4*)outb)[ix] = make_float4((float)x1, (float)y1, (float)x2, (float)y2);
    }
}

// ---------------- S2: mask matrix from staged boxes (coalesced) -----------------

__global__ __launch_bounds__(256) void k_mask(
    const double4* __restrict__ rawbox, const float* __restrict__ clsall,
    const double* __restrict__ pmax,
    uint64_t* __restrict__ M, uint64_t* __restrict__ D,
    uint32_t* __restrict__ Rnz)
{
    __shared__ double lx1[1024], ly1[1024], lx2[1024], ly2[1024], lar[1024];
    __shared__ float fx1[1024], fy1[1024], fx2[1024], fy2[1024];
    __shared__ uint64_t ornz[4][64];
    int bid = blockIdx.x;
    int b = bid >> 4, rb = bid & 15;
    int tid = threadIdx.x;

    double offscale = pmax[b] + 1.0;

    for (int t = tid; t < 1024; t += 256) {
        size_t ix = (size_t)b * 1024 + t;
        double4 rb4 = rawbox[ix];
        double o = (double)clsall[ix] * offscale;
        double ox1 = rb4.x + o, oy1 = rb4.y + o;
        double ox2 = rb4.z + o, oy2 = rb4.w + o;
        lx1[t] = ox1; ly1[t] = oy1; lx2[t] = ox2; ly2[t] = oy2;
        lar[t] = (ox2 - ox1 + 1.0) * (oy2 - oy1 + 1.0);
        fx1[t] = (float)ox1; fy1[t] = (float)oy1;
        fx2[t] = (float)ox2; fy2[t] = (float)oy2;
    }
    __syncthreads();

    // lane = row, wave = 4-word column slice; all inner-loop LDS reads are
    // wave-uniform broadcasts. f32 conservative prefilter (margin -0.5 >>
    // conversion error); exact f64 IoU only for rare passers.
    int ww = tid >> 6;
    int l  = tid & 63;
    int r  = rb * 64 + l;
    float frx1 = fx1[r], fry1 = fy1[r], frx2 = fx2[r], fry2 = fy2[r];
    double rx1 = lx1[r], ry1 = ly1[r], rx2 = lx2[r], ry2 = ly2[r], ra = lar[r];
    int wbase = ww * 4;

    uint64_t bits0 = 0, bits1 = 0, bits2 = 0, bits3 = 0;

#define COLWORD(Q, BITS)                                                       \
    {                                                                          \
        int cb = (wbase + (Q)) * 64;                                           \
        if (cb + 63 > r) {                                                     \
            for (int kk = 0; kk < 64; ++kk) {                                  \
                int j = cb + kk;                                               \
                float xm = fminf(fx2[j], frx2) - fmaxf(fx1[j], frx1);          \
                float ym = fminf(fy2[j], fry2) - fmaxf(fy1[j], fry1);          \
                if (xm > -0.5f && ym > -0.5f) {                                \
                    double xmn = fmax(lx1[j], rx1);                            \
                    double ymn = fmax(ly1[j], ry1);                            \
                    double xmx = fmin(lx2[j], rx2);                            \
                    double ymx = fmin(ly2[j], ry2);                            \
                    double iw = xmx - xmn; iw = iw < 0.0 ? 0.0 : iw;           \
                    double ih = ymx - ymn; ih = ih < 0.0 ? 0.0 : ih;           \
                    double inter = iw * ih;                                    \
                    double iou = inter / (ra + lar[j] - inter);                \
                    BITS |= ((uint64_t)((j > r) && (iou > D_IOU_THR))) << kk;  \
                }                                                              \
            }                                                                  \
        }                                                                      \
    }

    COLWORD(0, bits0) COLWORD(1, bits1) COLWORD(2, bits2) COLWORD(3, bits3)
#undef COLWORD

    size_t mrow = ((size_t)b * 1024 + r) * 16 + wbase;
    M[mrow + 0] = bits0; M[mrow + 1] = bits1;
    M[mrow + 2] = bits2; M[mrow + 3] = bits3;

    if (ww == (rb >> 2)) {
        uint64_t db = (rb & 3) == 0 ? bits0 : (rb & 3) == 1 ? bits1
                    : (rb & 3) == 2 ? bits2 : bits3;
        D[((size_t)b * 16 + rb) * 64 + l] = db;
    }

    ornz[ww][l] = bits0 | bits1 | bits2 | bits3;
    __syncthreads();
    if (ww == 0) {
        uint64_t o = ornz[0][l] | ornz[1][l] | ornz[2][l] | ornz[3][l];
        Rnz[(size_t)b * 1024 + r] = (o != 0) ? 1u : 0u;
    }
}

// ---------------- S3: one-wave sparse scan ----------------

#define LOADC(G)                                                               \
    C0  = Mb[((size_t)(G) * 64 +  0 + p) * 16 + w];                            \
    C1  = Mb[((size_t)(G) * 64 +  4 + p) * 16 + w];                            \
    C2  = Mb[((size_t)(G) * 64 +  8 + p) * 16 + w];                            \
    C3  = Mb[((size_t)(G) * 64 + 12 + p) * 16 + w];                            \
    C4  = Mb[((size_t)(G) * 64 + 16 + p) * 16 + w];                            \
    C5  = Mb[((size_t)(G) * 64 + 20 + p) * 16 + w];                            \
    C6  = Mb[((size_t)(G) * 64 + 24 + p) * 16 + w];                            \
    C7  = Mb[((size_t)(G) * 64 + 28 + p) * 16 + w];                            \
    C8  = Mb[((size_t)(G) * 64 + 32 + p) * 16 + w];                            \
    C9  = Mb[((size_t)(G) * 64 + 36 + p) * 16 + w];                            \
    C10 = Mb[((size_t)(G) * 64 + 40 + p) * 16 + w];                            \
    C11 = Mb[((size_t)(G) * 64 + 44 + p) * 16 + w];                            \
    C12 = Mb[((size_t)(G) * 64 + 48 + p) * 16 + w];                            \
    C13 = Mb[((size_t)(G) * 64 + 52 + p) * 16 + w];                            \
    C14 = Mb[((size_t)(G) * 64 + 56 + p) * 16 + w];                            \
    C15 = Mb[((size_t)(G) * 64 + 60 + p) * 16 + w];

#define APPLY_Q(q)                                                             \
    {                                                                          \
        uint64_t t_ = (alive >> (4 * (q) + p)) & 1ull;                         \
        acc &= ~(C##q & (0ull - t_));                                          \
    }

#define STEPG(G)                                                               \
    {                                                                          \
        uint64_t kg = rl64(kw, (G));                                           \
        if (kg & nz##G) {                                                      \
            uint64_t dg = Dp[(size_t)(G) * 64 + lane];                         \
            LOADC(G)                                                           \
            uint64_t cur = kg, it = kg & nz##G;                                \
            while (it) {                                                       \
                int kk = __builtin_ctzll(it);                                  \
                uint64_t dk = rl64(dg, kk);                                    \
                cur &= ~dk;                                                    \
                it &= ~dk;                                                     \
                it &= it - 1ull;                                               \
            }                                                                  \
            uint64_t alive = cur;                                              \
            uint64_t acc = ~0ull;                                              \
            APPLY_Q(0)  APPLY_Q(1)  APPLY_Q(2)  APPLY_Q(3)                     \
            APPLY_Q(4)  APPLY_Q(5)  APPLY_Q(6)  APPLY_Q(7)                     \
            APPLY_Q(8)  APPLY_Q(9)  APPLY_Q(10) APPLY_Q(11)                    \
            APPLY_Q(12) APPLY_Q(13) APPLY_Q(14) APPLY_Q(15)                    \
            acc &= __shfl_xor(acc, 16, 64);                                    \
            acc &= __shfl_xor(acc, 32, 64);                                    \
            kw &= acc;                                                         \
        }                                                                      \
    }

__global__ __launch_bounds__(64, 1) void k_scan(
    const uint64_t* __restrict__ M, const uint64_t* __restrict__ D,
    const uint32_t* __restrict__ Rnz, const uint64_t* __restrict__ keepw,
    const float* __restrict__ outs, const float* __restrict__ outc,
    const float* __restrict__ outb, float* __restrict__ out)
{
    int b = blockIdx.x;
    int lane = threadIdx.x;          // one wave
    int p = (lane >> 4) & 3;         // replica 0..3
    int w = lane & 15;               // word index
    const uint64_t* Mb = M + (size_t)b * 1024 * 16;
    const uint64_t* Dp = D + (size_t)b * 1024;
    const uint32_t* Rp = Rnz + (size_t)b * 1024;

    uint64_t kw = keepw[(size_t)b * 16 + w];   // word w, replicated x4

    uint32_t f0  = Rp[0 * 64 + lane],  f1  = Rp[1 * 64 + lane];
    uint32_t f2  = Rp[2 * 64 + lane],  f3  = Rp[3 * 64 + lane];
    uint32_t f4  = Rp[4 * 64 + lane],  f5  = Rp[5 * 64 + lane];
    uint32_t f6  = Rp[6 * 64 + lane],  f7  = Rp[7 * 64 + lane];
    uint32_t f8  = Rp[8 * 64 + lane],  f9  = Rp[9 * 64 + lane];
    uint32_t f10 = Rp[10 * 64 + lane], f11 = Rp[11 * 64 + lane];
    uint32_t f12 = Rp[12 * 64 + lane], f13 = Rp[13 * 64 + lane];
    uint32_t f14 = Rp[14 * 64 + lane], f15 = Rp[15 * 64 + lane];
    uint64_t nz0  = __ballot(f0 != 0),  nz1  = __ballot(f1 != 0);
    uint64_t nz2  = __ballot(f2 != 0),  nz3  = __ballot(f3 != 0);
    uint64_t nz4  = __ballot(f4 != 0),  nz5  = __ballot(f5 != 0);
    uint64_t nz6  = __ballot(f6 != 0),  nz7  = __ballot(f7 != 0);
    uint64_t nz8  = __ballot(f8 != 0),  nz9  = __ballot(f9 != 0);
    uint64_t nz10 = __ballot(f10 != 0), nz11 = __ballot(f11 != 0);
    uint64_t nz12 = __ballot(f12 != 0), nz13 = __ballot(f13 != 0);
    uint64_t nz14 = __ballot(f14 != 0), nz15 = __ballot(f15 != 0);

    uint64_t C0,C1,C2,C3,C4,C5,C6,C7,C8,C9,C10,C11,C12,C13,C14,C15;

    STEPG(0)  STEPG(1)  STEPG(2)  STEPG(3)
    STEPG(4)  STEPG(5)  STEPG(6)  STEPG(7)
    STEPG(8)  STEPG(9)  STEPG(10) STEPG(11)
    STEPG(12) STEPG(13) STEPG(14) STEPG(15)

#pragma unroll
    for (int t = 0; t < 16; ++t) {
        int j = t * 64 + lane;
        uint64_t kwt = rl64(kw, t);
        bool kp = (kwt >> lane) & 1ull;
        if (j < KTOP) {
            size_t ix = (size_t)b * 1024 + j;
            out[(size_t)b * KTOP + j] = kp ? outs[ix] : 0.0f;
            out[(size_t)NB * KTOP + (size_t)b * KTOP + j] = kp ? outc[ix] : 0.0f;
            float4 bb = kp ? ((const float4*)outb)[ix] : make_float4(0.f, 0.f, 0.f, 0.f);
            ((float4*)(out + 2 * (size_t)NB * KTOP))[(size_t)b * KTOP + j] = bb;
        }
    }
}

// ---------------- launch ----------------

extern "C" void kernel_launch(void* const* d_in, const int* in_sizes, int n_in,
                              void* d_out, int out_size, void* d_ws, size_t ws_size,
                              hipStream_t stream) {
    const float* cls[5];
    const float* cnt[5];
    const float* reg[5];
    for (int i = 0; i < 5; ++i) {
        cls[i] = (const float*)d_in[i];
        cnt[i] = (const float*)d_in[5 + i];
        reg[i] = (const float*)d_in[10 + i];
    }
    float* out = (float*)d_out;

    // ws layout (bytes); M reuses the packed region (packed dead after k_selprep)
    char* ws = (char*)d_ws;
    uint64_t* packed  = (uint64_t*)(ws + 0);          // 8*16384*8     = 1,048,576
    uint64_t* M       = (uint64_t*)(ws + 0);          // 8*1024*16*8   = 1,048,576 (reuse)
    int*      classes = (int*)     (ws + 1048576);    // 8*13343*4     =   426,976
    double4*  rawbox  = (double4*) (ws + 1475552);    // 8*1024*32     =   262,144
    float*    clsall  = (float*)   (ws + 1737696);    // 8*1024*4      =    32,768
    double*   pmax    = (double*)  (ws + 1770464);    // 8*8           =        64
    uint64_t* keepw   = (uint64_t*)(ws + 1770528);    // 8*16*8        =     1,024
    uint64_t* D       = (uint64_t*)(ws + 1771552);    // 8*16*64*8     =    65,536
    uint32_t* Rnz     = (uint32_t*)(ws + 1837088);    // 8*1024*4      =    32,768
    float*    outs    = (float*)   (ws + 1869856);    // 8*1024*4      =    32,768
    float*    outc    = (float*)   (ws + 1902624);    // 8*1024*4      =    32,768
    float*    outb    = (float*)   (ws + 1935392);    // 8*1024*16     =   131,072

    k_scores<<<(NB * PPAD) / 256, 256, 0, stream>>>(
        cls[0], cls[1], cls[2], cls[3], cls[4],
        cnt[0], cnt[1], cnt[2], cnt[3], cnt[4],
        packed, classes);

    k_selprep<<<NB, 1024, 0, stream>>>(packed, classes,
                                       reg[0], reg[1], reg[2], reg[3], reg[4],
                                       rawbox, clsall, outs, outc, outb, keepw, pmax);

    k_mask<<<NB * 16, 256, 0, stream>>>(rawbox, clsall, pmax, M, D, Rnz);

    k_scan<<<NB, 64, 0, stream>>>(M, D, Rnz, keepw, outs, outc, outb, out);
}